// Round 1
// 568.863 us; speedup vs baseline: 1.0962x; 1.0962x over previous
//
#include <hip/hip_runtime.h>
#include <math.h>

// B=4, N=4096, C=1024, KV=1024, H=4, Ch=Kh=256
// z = (path<<4) | (b<<2) | h  for 32-group stages.
// path0 (O1): Xm=emb_alld, Xn=emb1, Wq, Wkd0, Wvd0, Wout, obig X=emb_alld
// path1 (Od1): Xm=emb_all, Xn=embd1, Wqd, Wk0, Wv0, Woutd, obig X=emb_all
// Chain: GT = Xm^T@Xn (per z) -> T = Wq@ (GT as B) -> S = T@Wk^T (*1/32)
//        p = softmax(instnorm(S)) -> PT = WvT@p^T -> Mb = WoutR@PT^T -> O = X@Mb^T

#define PITCH 40

typedef __bf16 bf16x4 __attribute__((ext_vector_type(4)));
typedef __bf16 bf16x8 __attribute__((ext_vector_type(8)));
typedef float f32x4 __attribute__((ext_vector_type(4)));

__device__ inline void gl2lds16(const void* g, void* l) {
    __builtin_amdgcn_global_load_lds(
        (const __attribute__((address_space(1))) unsigned int*)g,
        (__attribute__((address_space(3))) unsigned int*)l, 16, 0, 0);
}

// ---------------- prep: X fp32 -> bf16 ----------------
__global__ __launch_bounds__(256) void prep_x(const float* __restrict__ emb_all,
                                              const float* __restrict__ emb_alld,
                                              __bf16* __restrict__ Xb) {
    const float* src = blockIdx.y ? emb_alld : emb_all;
    __bf16* dst = Xb + (long long)blockIdx.y * 16777216;
    long long i4 = (long long)blockIdx.x * 256 + threadIdx.x;
    float4 v = *(const float4*)&src[i4 * 4];
    bf16x4 o = {(__bf16)v.x, (__bf16)v.y, (__bf16)v.z, (__bf16)v.w};
    *(bf16x4*)&dst[i4 * 4] = o;
}

// ---------------- prep: weights -> bf16 (+transpose/gather) ----------------
__global__ __launch_bounds__(256) void prep_w(
    const float* __restrict__ Wq, const float* __restrict__ Wqd,
    const float* __restrict__ Wk0, const float* __restrict__ Wv0,
    const float* __restrict__ Wkd0, const float* __restrict__ Wvd0,
    const float* __restrict__ Wout, const float* __restrict__ Woutd,
    __bf16* __restrict__ Wq_bf, __bf16* __restrict__ Wk_bf,
    __bf16* __restrict__ WvT_bf, __bf16* __restrict__ WoutR_bf)
{
    int id = blockIdx.x * 256 + threadIdx.x;
    if (id < 524288) {
        Wq_bf[id] = (__bf16)(id < 262144 ? Wq[id] : Wqd[id - 262144]);
    } else if (id < 655360) {
        int j = id - 524288;
        Wk_bf[j] = (__bf16)(j < 65536 ? Wkd0[j] : Wk0[j - 65536]);
    } else if (id < 786432) {
        int j = id - 655360;
        int p = j >> 16, r = (j >> 8) & 255, c2 = j & 255;
        const float* s = p ? Wv0 : Wvd0;
        WvT_bf[j] = (__bf16)s[c2 * 256 + r];   // WvT[m][k'] = Wv'[k'][m]
    } else if (id < 2883584) {
        int j = id - 786432;
        int p = j >> 20; int rem = j & 1048575; int h = rem >> 18; int oc = rem & 262143;
        int o = oc >> 8, c = oc & 255;
        const float* s = p ? Woutd : Wout;
        WoutR_bf[j] = (__bf16)s[o * 1024 + c * 4 + h];
    }
}

// ---------------- gram: GT partials = Xm^T @ Xn (fp32 in, split-K x4) ----------------
__global__ __launch_bounds__(256) void gram_mfma(
    const float* __restrict__ emb1, const float* __restrict__ emb_all,
    const float* __restrict__ embd1, const float* __restrict__ emb_alld,
    float* __restrict__ Gpart)
{
    __shared__ __bf16 As[128 * PITCH];
    __shared__ __bf16 Bs[128 * PITCH];

    const int z = blockIdx.z;
    const int path = z >> 4, bh = z & 15;
    const int b = bh >> 2, h = bh & 3;
    const float* Xm = (path == 0 ? emb_alld : emb_all) + (long long)b * 4194304 + h * 256;
    const float* Xn = (path == 0 ? emb1     : embd1)   + (long long)b * 4194304 + h * 256;

    const int i0 = (blockIdx.x >> 1) * 128;
    const int j0 = (blockIdx.x & 1) * 128;
    const int kb0 = blockIdx.y * 1024;

    const int t = threadIdx.x;
    const int q  = t & 7;
    const int i4 = t >> 3;
    const int lane = t & 63;
    const int wave = t >> 6;
    const int wr = (wave >> 1) * 64, wc = (wave & 1) * 64;
    const int fm = lane & 15, fg = lane >> 4;

    f32x4 acc[4][4];
#pragma unroll
    for (int u = 0; u < 4; ++u)
#pragma unroll
        for (int v = 0; v < 4; ++v) acc[u][v] = (f32x4){0.f, 0.f, 0.f, 0.f};

    for (int kb = kb0; kb < kb0 + 1024; kb += 32) {
        float4 va[4], vb[4];
        const float* pa = Xm + (long long)(kb + q * 4) * 1024 + i0 + i4 * 4;
        const float* pb = Xn + (long long)(kb + q * 4) * 1024 + j0 + i4 * 4;
#pragma unroll
        for (int r = 0; r < 4; ++r) {
            va[r] = *(const float4*)(pa + (long long)r * 1024);
            vb[r] = *(const float4*)(pb + (long long)r * 1024);
        }
        __syncthreads();
#pragma unroll
        for (int c = 0; c < 4; ++c) {
            bf16x4 wa, wb;
#pragma unroll
            for (int r = 0; r < 4; ++r) {
                wa[r] = (__bf16)(((const float*)&va[r])[c]);
                wb[r] = (__bf16)(((const float*)&vb[r])[c]);
            }
            *(bf16x4*)&As[(i4 * 4 + c) * PITCH + q * 4] = wa;
            *(bf16x4*)&Bs[(i4 * 4 + c) * PITCH + q * 4] = wb;
        }
        __syncthreads();

        bf16x8 af[4], bfv[4];
#pragma unroll
        for (int mt = 0; mt < 4; ++mt)
            af[mt] = *(const bf16x8*)&As[(wr + mt * 16 + fm) * PITCH + fg * 8];
#pragma unroll
        for (int nt = 0; nt < 4; ++nt)
            bfv[nt] = *(const bf16x8*)&Bs[(wc + nt * 16 + fm) * PITCH + fg * 8];
#pragma unroll
        for (int mt = 0; mt < 4; ++mt)
#pragma unroll
            for (int nt = 0; nt < 4; ++nt)
                acc[mt][nt] = __builtin_amdgcn_mfma_f32_16x16x32_bf16(af[mt], bfv[nt], acc[mt][nt], 0, 0, 0);
    }

    float* Gp = Gpart + ((long long)blockIdx.y * 32 + z) * 65536;
    const int col = lane & 15, rq = (lane >> 4) * 4;
#pragma unroll
    for (int mt = 0; mt < 4; ++mt)
#pragma unroll
        for (int nt = 0; nt < 4; ++nt)
#pragma unroll
            for (int r = 0; r < 4; ++r)
                Gp[(i0 + wr + mt * 16 + rq + r) * 256 + (j0 + wc + nt * 16 + col)] = acc[mt][nt][r];
}

__global__ __launch_bounds__(256) void reduce_g(const float* __restrict__ Gpart, __bf16* __restrict__ GT) {
    long long idx4 = (long long)blockIdx.x * 256 + threadIdx.x;   // < 524288
    float4 a = *(const float4*)&Gpart[idx4 * 4];
    float4 b = *(const float4*)&Gpart[2097152 + idx4 * 4];
    float4 c = *(const float4*)&Gpart[4194304 + idx4 * 4];
    float4 d = *(const float4*)&Gpart[6291456 + idx4 * 4];
    bf16x4 o;
    o[0] = (__bf16)(a.x + b.x + c.x + d.x);
    o[1] = (__bf16)(a.y + b.y + c.y + d.y);
    o[2] = (__bf16)(a.z + b.z + c.z + d.z);
    o[3] = (__bf16)(a.w + b.w + c.w + d.w);
    *(bf16x4*)&GT[idx4 * 4] = o;
}

// ---------------- generic NT MFMA: C[z] = alpha * A[z] @ B[z]^T ----------------
template <typename CT>
__global__ __launch_bounds__(256) void mfma_nt(
    const __bf16* __restrict__ A, const __bf16* __restrict__ B, CT* __restrict__ C,
    int mtiles, int K,
    long long a1, long long a2, long long a3,
    long long b1, long long b2, long long b3,
    long long c1, long long c2, long long c3,
    int cpitch, float alpha)
{
    __shared__ __bf16 As[64 * 32];
    __shared__ __bf16 Bs[64 * 32];
    const int z = blockIdx.y;
    const __bf16* Az = A + (long long)(z >> 4) * a1 + (long long)((z >> 2) & 3) * a2 + (long long)(z & 3) * a3;
    const __bf16* Bz = B + (long long)(z >> 4) * b1 + (long long)((z >> 2) & 3) * b2 + (long long)(z & 3) * b3;
    CT* Cz = C + (long long)(z >> 4) * c1 + (long long)((z >> 2) & 3) * c2 + (long long)(z & 3) * c3;

    const int tm = blockIdx.x % mtiles, tn = blockIdx.x / mtiles;
    const int t = threadIdx.x;
    const int lane = t & 63, wave = t >> 6;
    const int row = t >> 2, ch = t & 3;
    const int fm = lane & 15, fg = lane >> 4;

    const __bf16* ga = Az + (long long)(tm * 64 + row) * K + ch * 8;
    const __bf16* gb = Bz + (long long)(tn * 64 + row) * K + ch * 8;
    __bf16* la = &As[t * 8];
    __bf16* lb = &Bs[t * 8];

    f32x4 acc[4];
#pragma unroll
    for (int u = 0; u < 4; ++u) acc[u] = (f32x4){0.f, 0.f, 0.f, 0.f};

    for (int kb = 0; kb < K; kb += 32) {
        __syncthreads();
        gl2lds16(ga + kb, la);
        gl2lds16(gb + kb, lb);
        __syncthreads();
        bf16x8 bv = *(const bf16x8*)&Bs[(wave * 16 + fm) * 32 + fg * 8];
#pragma unroll
        for (int mt = 0; mt < 4; ++mt) {
            bf16x8 av = *(const bf16x8*)&As[(mt * 16 + fm) * 32 + fg * 8];
            acc[mt] = __builtin_amdgcn_mfma_f32_16x16x32_bf16(av, bv, acc[mt], 0, 0, 0);
        }
    }

    const int colc = tn * 64 + wave * 16 + fm;
    const int rq = fg * 4;
#pragma unroll
    for (int mt = 0; mt < 4; ++mt)
#pragma unroll
        for (int r = 0; r < 4; ++r) {
            int rowc = tm * 64 + mt * 16 + rq + r;
            Cz[(long long)rowc * cpitch + colc] = (CT)(acc[mt][r] * alpha);
        }
}

// ---------------- obig: O = X @ Mb^T, 256x256 tile, 8 waves, BK=64, 8-phase style ----
// T2 swizzle: storage col = logical col ^ ((row&7)<<3)   (elements, 8-elem=16B blocks)
// applied on global SOURCE of global_load_lds (linear LDS dest) + on ds_read side.
// Staging half-tiles match per-wave quadrant consumption:
//   A half h = rows {h*64..h*64+63} u {128+h*64..128+h*64+63}
//   B half h = rows with (row mod 64) in [h*32, h*32+32)
// vmcnt counted (4) in steady state, never 0 until the last tile.

#define VMCNT4 asm volatile("s_waitcnt vmcnt(4)" ::: "memory")
#define VMCNT2 asm volatile("s_waitcnt vmcnt(2)" ::: "memory")
#define VMCNT0 asm volatile("s_waitcnt vmcnt(0)" ::: "memory")
#define BARR   asm volatile("s_barrier" ::: "memory")

#define STAGE_A(h, kt, c) do { \
    _Pragma("unroll") \
    for (int o = 0; o < 2; ++o) { \
        int rl = (h) * 64 + o * 128 + stg_row; \
        gl2lds16(Xa + (long long)rl * 1024 + (kt) * 64 + stg_col, \
                 &lds[(c) * 32768 + rl * 64 + lin_col]); \
    } \
} while (0)

#define STAGE_B(h, kt, c) do { \
    _Pragma("unroll") \
    for (int o = 0; o < 2; ++o) { \
        int rl = o * 128 + (h) * 32 + (stg_row & 31) + ((stg_row & 32) << 1); \
        gl2lds16(Bb + (long long)rl * 1024 + (kt) * 64 + stg_col, \
                 &lds[(c) * 32768 + 16384 + rl * 64 + lin_col]); \
    } \
} while (0)

#define LOAD_A(hm, c) do { \
    _Pragma("unroll") \
    for (int mt = 0; mt < 4; ++mt) { \
        const __bf16* p = &lds[(c) * 32768 + (wr * 128 + (hm) * 64 + mt * 16 + fm) * 64]; \
        af[mt][0] = *(const bf16x8*)&p[(fg * 8) ^ rsw]; \
        af[mt][1] = *(const bf16x8*)&p[(32 + fg * 8) ^ rsw]; \
    } \
} while (0)

#define LOAD_B(hn, c) do { \
    _Pragma("unroll") \
    for (int nt = 0; nt < 2; ++nt) { \
        const __bf16* p = &lds[(c) * 32768 + 16384 + (wc * 64 + (hn) * 32 + nt * 16 + fm) * 64]; \
        bv[(hn) * 2 + nt][0] = *(const bf16x8*)&p[(fg * 8) ^ rsw]; \
        bv[(hn) * 2 + nt][1] = *(const bf16x8*)&p[(32 + fg * 8) ^ rsw]; \
    } \
} while (0)

#define MFMA_Q(hm, hn) do { \
    __builtin_amdgcn_s_setprio(1); \
    _Pragma("unroll") \
    for (int mt = 0; mt < 4; ++mt) \
        _Pragma("unroll") \
        for (int nt = 0; nt < 2; ++nt) { \
            acc[(hm) * 4 + mt][(hn) * 2 + nt] = __builtin_amdgcn_mfma_f32_16x16x32_bf16( \
                af[mt][0], bv[(hn) * 2 + nt][0], acc[(hm) * 4 + mt][(hn) * 2 + nt], 0, 0, 0); \
            acc[(hm) * 4 + mt][(hn) * 2 + nt] = __builtin_amdgcn_mfma_f32_16x16x32_bf16( \
                af[mt][1], bv[(hn) * 2 + nt][1], acc[(hm) * 4 + mt][(hn) * 2 + nt], 0, 0, 0); \
        } \
    __builtin_amdgcn_s_setprio(0); \
} while (0)

__global__ __launch_bounds__(512, 2) void obig8(
    const __bf16* __restrict__ Xall, const __bf16* __restrict__ Mb, float* __restrict__ out)
{
    __shared__ __bf16 lds[65536];   // [A0 32KB][B0 32KB][A1 32KB][B1 32KB]

    const int id = blockIdx.x;                  // 0..511
    const int wg = (id & 7) * 64 + (id >> 3);   // bijective XCD swizzle: one z per XCD
    const int z = wg >> 6;                      // 0..7
    const int tile = wg & 63;
    const int tm = tile & 15, tn = tile >> 4;   // 16 m-tiles x 4 n-tiles
    const int path = z >> 2, b = z & 3;

    const __bf16* Xa = Xall + (path == 0 ? 16777216LL : 0LL)
                     + (long long)b * 4194304 + (long long)tm * 262144;
    const __bf16* Bb = Mb + (long long)path * 4194304 + (long long)b * 1048576
                     + (long long)tn * 262144;
    float* Ob = out + (long long)path * 16777216 + (long long)b * 4194304;

    const int t = threadIdx.x;
    const int lane = t & 63, wave = t >> 6;     // 8 waves: 2M x 4N
    const int wr = wave >> 2, wc = wave & 3;
    const int fm = lane & 15, fg = lane >> 4;
    const int stg_row = t >> 3;                 // 0..63
    const int lin_col = (t & 7) * 8;            // linear LDS dest col (elems)
    const int stg_col = ((t & 7) ^ (stg_row & 7)) * 8;  // inverse-swizzled global col
    const int rsw = (fm & 7) * 8;               // read-side swizzle XOR (elems)

    f32x4 acc[8][4];
#pragma unroll
    for (int u = 0; u < 8; ++u)
#pragma unroll
        for (int v = 0; v < 4; ++v) acc[u][v] = (f32x4){0.f, 0.f, 0.f, 0.f};

    bf16x8 af[4][2];   // current M-half: 4 mt x 2 ksub
    bf16x8 bv[8][2];   // whole tile's B: 4 nt x 2 ksub (both halves kept)

    // prologue: stage tile 0 into buf 0 in consumption order Ah0, Bh0, Bh1, Ah1
    STAGE_A(0, 0, 0);
    STAGE_B(0, 0, 0);
    STAGE_B(1, 0, 0);
    STAGE_A(1, 0, 0);
    VMCNT4;   // Ah0,Bh0 complete; Bh1,Ah1 in flight
    BARR;

    for (int kt = 0; kt < 15; ++kt) {
        const int c = kt & 1, n = c ^ 1;
        // ---- phase 1: quadrant (Mh0, Nh0) ----
        LOAD_A(0, c);
        LOAD_B(0, c);
        STAGE_A(0, kt + 1, n);
        VMCNT4;                 // drains Bh1(t) -> validates phase 2
        BARR;
        MFMA_Q(0, 0);
        BARR;
        // ---- phase 2: quadrant (Mh0, Nh1) ----
        LOAD_B(1, c);
        STAGE_B(0, kt + 1, n);
        VMCNT4;                 // drains Ah1(t) -> validates phase 3
        BARR;
        MFMA_Q(0, 1);
        BARR;
        // ---- phase 3: quadrant (Mh1, Nh1) ----
        LOAD_A(1, c);
        STAGE_B(1, kt + 1, n);
        BARR;                   // no vmcnt: phase 4 reads nothing new
        MFMA_Q(1, 1);
        BARR;
        // ---- phase 4: quadrant (Mh1, Nh0) ----
        STAGE_A(1, kt + 1, n);
        VMCNT4;                 // drains A'h0,B'h0 -> validates next tile's phase 1
        BARR;
        MFMA_Q(1, 0);
        BARR;
    }

    // ---- epilogue tile 15 (buf 1, no staging; drain 4 -> 2 -> 0) ----
    {
        LOAD_A(0, 1);
        LOAD_B(0, 1);
        VMCNT2;                 // drains Bh1(15)
        BARR;
        MFMA_Q(0, 0);
        BARR;
        LOAD_B(1, 1);
        VMCNT0;                 // drains Ah1(15)
        BARR;
        MFMA_Q(0, 1);
        BARR;
        LOAD_A(1, 1);
        MFMA_Q(1, 1);
        MFMA_Q(1, 0);
    }

    // ---- C write ----
    const int rq = fg * 4;
    float* op = Ob + (long long)(tm * 256 + wr * 128 + rq) * 1024 + tn * 256 + wc * 64 + fm;
#pragma unroll
    for (int mi = 0; mi < 8; ++mi)
#pragma unroll
        for (int ni = 0; ni < 4; ++ni)
#pragma unroll
            for (int r = 0; r < 4; ++r)
                op[(long long)(mi * 16 + r) * 1024 + ni * 16] = acc[mi][ni][r];
}

// ---------------- stats + softmax ----------------
__global__ __launch_bounds__(256) void stats_kernel(const float* __restrict__ S, float* __restrict__ st) {
    int pg = blockIdx.x;
    const float* s = S + (long long)pg * 65536;
    float sum = 0.f, sq = 0.f;
    for (int i = threadIdx.x; i < 65536; i += 256) {
        float v = s[i];
        sum += v;
        sq += v * v;
    }
#pragma unroll
    for (int off = 32; off; off >>= 1) {
        sum += __shfl_down(sum, off);
        sq  += __shfl_down(sq,  off);
    }
    __shared__ float r1[4], r2[4];
    int w = threadIdx.x >> 6;
    if ((threadIdx.x & 63) == 0) { r1[w] = sum; r2[w] = sq; }
    __syncthreads();
    if (threadIdx.x == 0) {
        float ts = r1[0] + r1[1] + r1[2] + r1[3];
        float tq = r2[0] + r2[1] + r2[2] + r2[3];
        float mean = ts * (1.0f / 65536.0f);
        float var = tq * (1.0f / 65536.0f) - mean * mean;
        st[pg * 2 + 0] = mean;
        st[pg * 2 + 1] = rsqrtf(var + 1e-5f);
    }
}

__global__ __launch_bounds__(256) void softmax_kernel(const float* __restrict__ S,
                                                      const float* __restrict__ st,
                                                      __bf16* __restrict__ p_bf) {
    int pg = blockIdx.y;
    int c = blockIdx.x;
    float mean = st[pg * 2 + 0], rstd = st[pg * 2 + 1];
    const float* row = S + (long long)pg * 65536 + c * 256;
    int t = threadIdx.x;
    float x = (row[t] - mean) * rstd;
    float m = x;
#pragma unroll
    for (int off = 32; off; off >>= 1) m = fmaxf(m, __shfl_down(m, off));
    __shared__ float r1[4], r2[4];
    int w = t >> 6;
    if ((t & 63) == 0) r1[w] = m;
    __syncthreads();
    m = fmaxf(fmaxf(r1[0], r1[1]), fmaxf(r1[2], r1[3]));
    float e = expf(x - m);
    float ssum = e;
#pragma unroll
    for (int off = 32; off; off >>= 1) ssum += __shfl_down(ssum, off);
    if ((t & 63) == 0) r2[w] = ssum;
    __syncthreads();
    ssum = r2[0] + r2[1] + r2[2] + r2[3];
    p_bf[(long long)pg * 65536 + c * 256 + t] = (__bf16)(e / ssum);
}

extern "C" void kernel_launch(void* const* d_in, const int* in_sizes, int n_in,
                              void* d_out, int out_size, void* d_ws, size_t ws_size,
                              hipStream_t stream) {
    const float* emb1     = (const float*)d_in[0];
    const float* emb_all  = (const float*)d_in[1];
    const float* embd1    = (const float*)d_in[2];
    const float* emb_alld = (const float*)d_in[3];
    const float* Wq    = (const float*)d_in[4];
    const float* Wqd   = (const float*)d_in[5];
    const float* Wk0   = (const float*)d_in[6];
    const float* Wv0   = (const float*)d_in[7];
    const float* Wkd0  = (const float*)d_in[8];
    const float* Wvd0  = (const float*)d_in[9];
    const float* Wout  = (const float*)d_in[10];
    const float* Woutd = (const float*)d_in[11];
    float* out = (float*)d_out;

    float* ws = (float*)d_ws;
    float*  Gpart   = ws;                             // 8,388,608 fl (dead after reduce_g)
    __bf16* Mb_bf   = (__bf16*)ws;                    // 8,388,608 bf16 (aliases Gpart)
    __bf16* X_bf    = (__bf16*)(ws + 8388608);        // 33,554,432 bf16 [emb_all | emb_alld]
    __bf16* GT_bf   = (__bf16*)(ws + 25165824);       // 2,097,152 bf16
    __bf16* T_bf    = (__bf16*)(ws + 26214400);       // 2,097,152 bf16
    float*  S       = ws + 27262976;                  // 2,097,152 fp32
    __bf16* p_bf    = (__bf16*)(ws + 29360128);       // 2,097,152 bf16
    __bf16* PT_bf   = (__bf16*)(ws + 30408704);       // 2,097,152 bf16
    __bf16* Wq_bf   = (__bf16*)(ws + 31457280);       // 524,288 bf16
    __bf16* Wk_bf   = (__bf16*)(ws + 31719424);       // 131,072 bf16
    __bf16* WvT_bf  = (__bf16*)(ws + 31784960);       // 131,072 bf16
    __bf16* WoutR_bf= (__bf16*)(ws + 31850496);       // 2,097,152 bf16
    float*  st      = ws + 32899072;                  // 64 fl  -> total ~131.6 MB

    dim3 blk(256);

    // prep
    prep_x<<<dim3(16384, 2), blk, 0, stream>>>(emb_all, emb_alld, X_bf);
    prep_w<<<11264, blk, 0, stream>>>(Wq, Wqd, Wk0, Wv0, Wkd0, Wvd0, Wout, Woutd,
                                      Wq_bf, Wk_bf, WvT_bf, WoutR_bf);

    // GT = Xm^T @ Xn (split-K x4) + reduce->bf16
    gram_mfma<<<dim3(4, 4, 32), blk, 0, stream>>>(emb1, emb_all, embd1, emb_alld, Gpart);
    reduce_g<<<2048, blk, 0, stream>>>(Gpart, GT_bf);

    // T = Wq_h @ G   (A=Wq_bf, B=GT)
    mfma_nt<__bf16><<<dim3(16, 32), blk, 0, stream>>>(
        Wq_bf, GT_bf, T_bf, 4, 256,
        262144, 0, 65536,  1048576, 262144, 65536,  1048576, 262144, 65536, 256, 1.0f);
    // S = scale * T @ Wk'^T
    mfma_nt<float><<<dim3(16, 32), blk, 0, stream>>>(
        T_bf, Wk_bf, S, 4, 256,
        1048576, 262144, 65536,  65536, 0, 0,  1048576, 262144, 65536, 256, 0.03125f);

    stats_kernel<<<32, blk, 0, stream>>>(S, st);
    softmax_kernel<<<dim3(256, 32), blk, 0, stream>>>(S, st, p_bf);

    // PT = WvT @ p^T
    mfma_nt<__bf16><<<dim3(16, 32), blk, 0, stream>>>(
        WvT_bf, p_bf, PT_bf, 4, 256,
        65536, 0, 0,  1048576, 262144, 65536,  1048576, 262144, 65536, 256, 1.0f);
    // Mb = WoutR @ PT^T   (M=1024)
    mfma_nt<__bf16><<<dim3(64, 32), blk, 0, stream>>>(
        WoutR_bf, PT_bf, Mb_bf, 16, 256,
        1048576, 0, 262144,  1048576, 262144, 65536,  4194304, 1048576, 256, 1024, 1.0f);

    // O = X @ Mb^T  (256x256 8-wave multi-phase, T2 swizzle, counted vmcnt)
    obig8<<<dim3(512), dim3(512), 0, stream>>>(X_bf, Mb_bf, out);
}

// Round 2
// 567.916 us; speedup vs baseline: 1.0980x; 1.0017x over previous
//
#include <hip/hip_runtime.h>
#include <math.h>

// B=4, N=4096, C=1024, KV=1024, H=4, Ch=Kh=256
// z = (path<<4) | (b<<2) | h  for 32-group stages.
// path0 (O1): Xm=emb_alld, Xn=emb1, Wq, Wkd0, Wvd0, Wout, obig X=emb_alld
// path1 (Od1): Xm=emb_all, Xn=embd1, Wqd, Wk0, Wv0, Woutd, obig X=emb_all
// Chain: GT = Xm^T@Xn (per z) -> T = Wq@ (GT as B) -> S = T@Wk^T (*1/32)
//        p = softmax(instnorm(S)) -> PT = WvT@p^T -> Mb = WoutR@PT^T -> O = X@Mb^T

#define PITCH 40

typedef __bf16 bf16x4 __attribute__((ext_vector_type(4)));
typedef __bf16 bf16x8 __attribute__((ext_vector_type(8)));
typedef float f32x4 __attribute__((ext_vector_type(4)));

__device__ inline void gl2lds16(const void* g, void* l) {
    __builtin_amdgcn_global_load_lds(
        (const __attribute__((address_space(1))) unsigned int*)g,
        (__attribute__((address_space(3))) unsigned int*)l, 16, 0, 0);
}

// ---------------- prep: X fp32 -> bf16 ----------------
__global__ __launch_bounds__(256) void prep_x(const float* __restrict__ emb_all,
                                              const float* __restrict__ emb_alld,
                                              __bf16* __restrict__ Xb) {
    const float* src = blockIdx.y ? emb_alld : emb_all;
    __bf16* dst = Xb + (long long)blockIdx.y * 16777216;
    long long i4 = (long long)blockIdx.x * 256 + threadIdx.x;
    float4 v = *(const float4*)&src[i4 * 4];
    bf16x4 o = {(__bf16)v.x, (__bf16)v.y, (__bf16)v.z, (__bf16)v.w};
    *(bf16x4*)&dst[i4 * 4] = o;
}

// ---------------- prep: weights -> bf16 (+transpose/gather) ----------------
__global__ __launch_bounds__(256) void prep_w(
    const float* __restrict__ Wq, const float* __restrict__ Wqd,
    const float* __restrict__ Wk0, const float* __restrict__ Wv0,
    const float* __restrict__ Wkd0, const float* __restrict__ Wvd0,
    const float* __restrict__ Wout, const float* __restrict__ Woutd,
    __bf16* __restrict__ Wq_bf, __bf16* __restrict__ Wk_bf,
    __bf16* __restrict__ WvT_bf, __bf16* __restrict__ WoutR_bf)
{
    int id = blockIdx.x * 256 + threadIdx.x;
    if (id < 524288) {
        Wq_bf[id] = (__bf16)(id < 262144 ? Wq[id] : Wqd[id - 262144]);
    } else if (id < 655360) {
        int j = id - 524288;
        Wk_bf[j] = (__bf16)(j < 65536 ? Wkd0[j] : Wk0[j - 65536]);
    } else if (id < 786432) {
        int j = id - 655360;
        int p = j >> 16, r = (j >> 8) & 255, c2 = j & 255;
        const float* s = p ? Wv0 : Wvd0;
        WvT_bf[j] = (__bf16)s[c2 * 256 + r];   // WvT[m][k'] = Wv'[k'][m]
    } else if (id < 2883584) {
        int j = id - 786432;
        int p = j >> 20; int rem = j & 1048575; int h = rem >> 18; int oc = rem & 262143;
        int o = oc >> 8, c = oc & 255;
        const float* s = p ? Woutd : Wout;
        WoutR_bf[j] = (__bf16)s[o * 1024 + c * 4 + h];
    }
}

// ---------------- gram: GT partials = Xm^T @ Xn (fp32 in, split-K x4) ----------------
__global__ __launch_bounds__(256) void gram_mfma(
    const float* __restrict__ emb1, const float* __restrict__ emb_all,
    const float* __restrict__ embd1, const float* __restrict__ emb_alld,
    float* __restrict__ Gpart)
{
    __shared__ __bf16 As[128 * PITCH];
    __shared__ __bf16 Bs[128 * PITCH];

    const int z = blockIdx.z;
    const int path = z >> 4, bh = z & 15;
    const int b = bh >> 2, h = bh & 3;
    const float* Xm = (path == 0 ? emb_alld : emb_all) + (long long)b * 4194304 + h * 256;
    const float* Xn = (path == 0 ? emb1     : embd1)   + (long long)b * 4194304 + h * 256;

    const int i0 = (blockIdx.x >> 1) * 128;
    const int j0 = (blockIdx.x & 1) * 128;
    const int kb0 = blockIdx.y * 1024;

    const int t = threadIdx.x;
    const int q  = t & 7;
    const int i4 = t >> 3;
    const int lane = t & 63;
    const int wave = t >> 6;
    const int wr = (wave >> 1) * 64, wc = (wave & 1) * 64;
    const int fm = lane & 15, fg = lane >> 4;

    f32x4 acc[4][4];
#pragma unroll
    for (int u = 0; u < 4; ++u)
#pragma unroll
        for (int v = 0; v < 4; ++v) acc[u][v] = (f32x4){0.f, 0.f, 0.f, 0.f};

    for (int kb = kb0; kb < kb0 + 1024; kb += 32) {
        float4 va[4], vb[4];
        const float* pa = Xm + (long long)(kb + q * 4) * 1024 + i0 + i4 * 4;
        const float* pb = Xn + (long long)(kb + q * 4) * 1024 + j0 + i4 * 4;
#pragma unroll
        for (int r = 0; r < 4; ++r) {
            va[r] = *(const float4*)(pa + (long long)r * 1024);
            vb[r] = *(const float4*)(pb + (long long)r * 1024);
        }
        __syncthreads();
#pragma unroll
        for (int c = 0; c < 4; ++c) {
            bf16x4 wa, wb;
#pragma unroll
            for (int r = 0; r < 4; ++r) {
                wa[r] = (__bf16)(((const float*)&va[r])[c]);
                wb[r] = (__bf16)(((const float*)&vb[r])[c]);
            }
            *(bf16x4*)&As[(i4 * 4 + c) * PITCH + q * 4] = wa;
            *(bf16x4*)&Bs[(i4 * 4 + c) * PITCH + q * 4] = wb;
        }
        __syncthreads();

        bf16x8 af[4], bfv[4];
#pragma unroll
        for (int mt = 0; mt < 4; ++mt)
            af[mt] = *(const bf16x8*)&As[(wr + mt * 16 + fm) * PITCH + fg * 8];
#pragma unroll
        for (int nt = 0; nt < 4; ++nt)
            bfv[nt] = *(const bf16x8*)&Bs[(wc + nt * 16 + fm) * PITCH + fg * 8];
#pragma unroll
        for (int mt = 0; mt < 4; ++mt)
#pragma unroll
            for (int nt = 0; nt < 4; ++nt)
                acc[mt][nt] = __builtin_amdgcn_mfma_f32_16x16x32_bf16(af[mt], bfv[nt], acc[mt][nt], 0, 0, 0);
    }

    float* Gp = Gpart + ((long long)blockIdx.y * 32 + z) * 65536;
    const int col = lane & 15, rq = (lane >> 4) * 4;
#pragma unroll
    for (int mt = 0; mt < 4; ++mt)
#pragma unroll
        for (int nt = 0; nt < 4; ++nt)
#pragma unroll
            for (int r = 0; r < 4; ++r)
                Gp[(i0 + wr + mt * 16 + rq + r) * 256 + (j0 + wc + nt * 16 + col)] = acc[mt][nt][r];
}

__global__ __launch_bounds__(256) void reduce_g(const float* __restrict__ Gpart, __bf16* __restrict__ GT) {
    long long idx4 = (long long)blockIdx.x * 256 + threadIdx.x;   // < 524288
    float4 a = *(const float4*)&Gpart[idx4 * 4];
    float4 b = *(const float4*)&Gpart[2097152 + idx4 * 4];
    float4 c = *(const float4*)&Gpart[4194304 + idx4 * 4];
    float4 d = *(const float4*)&Gpart[6291456 + idx4 * 4];
    bf16x4 o;
    o[0] = (__bf16)(a.x + b.x + c.x + d.x);
    o[1] = (__bf16)(a.y + b.y + c.y + d.y);
    o[2] = (__bf16)(a.z + b.z + c.z + d.z);
    o[3] = (__bf16)(a.w + b.w + c.w + d.w);
    *(bf16x4*)&GT[idx4 * 4] = o;
}

// ---------------- generic NT MFMA: C[z] = alpha * A[z] @ B[z]^T ----------------
template <typename CT>
__global__ __launch_bounds__(256) void mfma_nt(
    const __bf16* __restrict__ A, const __bf16* __restrict__ B, CT* __restrict__ C,
    int mtiles, int K,
    long long a1, long long a2, long long a3,
    long long b1, long long b2, long long b3,
    long long c1, long long c2, long long c3,
    int cpitch, float alpha)
{
    __shared__ __bf16 As[64 * 32];
    __shared__ __bf16 Bs[64 * 32];
    const int z = blockIdx.y;
    const __bf16* Az = A + (long long)(z >> 4) * a1 + (long long)((z >> 2) & 3) * a2 + (long long)(z & 3) * a3;
    const __bf16* Bz = B + (long long)(z >> 4) * b1 + (long long)((z >> 2) & 3) * b2 + (long long)(z & 3) * b3;
    CT* Cz = C + (long long)(z >> 4) * c1 + (long long)((z >> 2) & 3) * c2 + (long long)(z & 3) * c3;

    const int tm = blockIdx.x % mtiles, tn = blockIdx.x / mtiles;
    const int t = threadIdx.x;
    const int lane = t & 63, wave = t >> 6;
    const int row = t >> 2, ch = t & 3;
    const int fm = lane & 15, fg = lane >> 4;

    const __bf16* ga = Az + (long long)(tm * 64 + row) * K + ch * 8;
    const __bf16* gb = Bz + (long long)(tn * 64 + row) * K + ch * 8;
    __bf16* la = &As[t * 8];
    __bf16* lb = &Bs[t * 8];

    f32x4 acc[4];
#pragma unroll
    for (int u = 0; u < 4; ++u) acc[u] = (f32x4){0.f, 0.f, 0.f, 0.f};

    for (int kb = 0; kb < K; kb += 32) {
        __syncthreads();
        gl2lds16(ga + kb, la);
        gl2lds16(gb + kb, lb);
        __syncthreads();
        bf16x8 bv = *(const bf16x8*)&Bs[(wave * 16 + fm) * 32 + fg * 8];
#pragma unroll
        for (int mt = 0; mt < 4; ++mt) {
            bf16x8 av = *(const bf16x8*)&As[(mt * 16 + fm) * 32 + fg * 8];
            acc[mt] = __builtin_amdgcn_mfma_f32_16x16x32_bf16(av, bv, acc[mt], 0, 0, 0);
        }
    }

    const int colc = tn * 64 + wave * 16 + fm;
    const int rq = fg * 4;
#pragma unroll
    for (int mt = 0; mt < 4; ++mt)
#pragma unroll
        for (int r = 0; r < 4; ++r) {
            int rowc = tm * 64 + mt * 16 + rq + r;
            Cz[(long long)rowc * cpitch + colc] = (CT)(acc[mt][r] * alpha);
        }
}

// ---------------- obig: O = X @ Mb^T, 256x256 tile, 8 waves, BK=64 ----------------
// 4 phases per K-tile (one C-quadrant each), T2 swizzle, T5 setprio.
// Deep pipeline (m201-style): prologue stages tiles 0+1; during tile t, stage
// tile t+2 into the *current* buffer over quadrants already consumed this tile
// (produce-after-consume within the double buffer). ONE vmcnt(8) per K-tile at
// phase 4 validates tile t+1's whole buffer; tile t+2's 8 loads stay in flight.
// Issue->consume depth: 4-7 phases (~600-1000 cy) covers L2/L3 latency.
//
// T2 swizzle: storage col = logical col ^ ((row&7)<<3)  (elements, 16B blocks),
// applied on global SOURCE of global_load_lds (linear LDS dest) + on ds_read.
// Staging half-tiles match per-wave quadrant consumption:
//   A half h = rows {h*64..h*64+63} u {128+h*64..128+h*64+63}
//   B half h = rows with (row mod 64) in [h*32, h*32+32)

#define VMCNT8 asm volatile("s_waitcnt vmcnt(8)" ::: "memory")
#define VMCNT0 asm volatile("s_waitcnt vmcnt(0)" ::: "memory")
#define BARR   asm volatile("s_barrier" ::: "memory")

#define STAGE_A(h, kt, c) do { \
    _Pragma("unroll") \
    for (int o = 0; o < 2; ++o) { \
        int rl = (h) * 64 + o * 128 + stg_row; \
        gl2lds16(Xa + (long long)rl * 1024 + (kt) * 64 + stg_col, \
                 &lds[(c) * 32768 + rl * 64 + lin_col]); \
    } \
} while (0)

#define STAGE_B(h, kt, c) do { \
    _Pragma("unroll") \
    for (int o = 0; o < 2; ++o) { \
        int rl = o * 128 + (h) * 32 + (stg_row & 31) + ((stg_row & 32) << 1); \
        gl2lds16(Bb + (long long)rl * 1024 + (kt) * 64 + stg_col, \
                 &lds[(c) * 32768 + 16384 + rl * 64 + lin_col]); \
    } \
} while (0)

#define LOAD_A(hm, c) do { \
    _Pragma("unroll") \
    for (int mt = 0; mt < 4; ++mt) { \
        const __bf16* p = &lds[(c) * 32768 + (wr * 128 + (hm) * 64 + mt * 16 + fm) * 64]; \
        af[mt][0] = *(const bf16x8*)&p[(fg * 8) ^ rsw]; \
        af[mt][1] = *(const bf16x8*)&p[(32 + fg * 8) ^ rsw]; \
    } \
} while (0)

#define LOAD_B(hn, c) do { \
    _Pragma("unroll") \
    for (int nt = 0; nt < 2; ++nt) { \
        const __bf16* p = &lds[(c) * 32768 + 16384 + (wc * 64 + (hn) * 32 + nt * 16 + fm) * 64]; \
        bv[(hn) * 2 + nt][0] = *(const bf16x8*)&p[(fg * 8) ^ rsw]; \
        bv[(hn) * 2 + nt][1] = *(const bf16x8*)&p[(32 + fg * 8) ^ rsw]; \
    } \
} while (0)

#define MFMA_Q(hm, hn) do { \
    __builtin_amdgcn_s_setprio(1); \
    _Pragma("unroll") \
    for (int mt = 0; mt < 4; ++mt) \
        _Pragma("unroll") \
        for (int nt = 0; nt < 2; ++nt) { \
            acc[(hm) * 4 + mt][(hn) * 2 + nt] = __builtin_amdgcn_mfma_f32_16x16x32_bf16( \
                af[mt][0], bv[(hn) * 2 + nt][0], acc[(hm) * 4 + mt][(hn) * 2 + nt], 0, 0, 0); \
            acc[(hm) * 4 + mt][(hn) * 2 + nt] = __builtin_amdgcn_mfma_f32_16x16x32_bf16( \
                af[mt][1], bv[(hn) * 2 + nt][1], acc[(hm) * 4 + mt][(hn) * 2 + nt], 0, 0, 0); \
        } \
    __builtin_amdgcn_s_setprio(0); \
} while (0)

__global__ __launch_bounds__(512, 2) void obig8(
    const __bf16* __restrict__ Xall, const __bf16* __restrict__ Mb, float* __restrict__ out)
{
    __shared__ __bf16 lds[65536];   // [buf0: A 32KB | B 32KB][buf1: A 32KB | B 32KB]

    const int id = blockIdx.x;                  // 0..511
    const int wg = (id & 7) * 64 + (id >> 3);   // bijective XCD swizzle: one z per XCD
    const int z = wg >> 6;                      // 0..7
    const int tile = wg & 63;
    const int tm = tile & 15, tn = tile >> 4;   // 16 m-tiles x 4 n-tiles
    const int path = z >> 2, b = z & 3;

    const __bf16* Xa = Xall + (path == 0 ? 16777216LL : 0LL)
                     + (long long)b * 4194304 + (long long)tm * 262144;
    const __bf16* Bb = Mb + (long long)path * 4194304 + (long long)b * 1048576
                     + (long long)tn * 262144;
    float* Ob = out + (long long)path * 16777216 + (long long)b * 4194304;

    const int t = threadIdx.x;
    const int lane = t & 63, wave = t >> 6;     // 8 waves: 2M x 4N
    const int wr = wave >> 2, wc = wave & 3;
    const int fm = lane & 15, fg = lane >> 4;
    const int stg_row = t >> 3;                 // 0..63
    const int lin_col = (t & 7) * 8;            // linear LDS dest col (elems)
    const int stg_col = ((t & 7) ^ (stg_row & 7)) * 8;  // inverse-swizzled global col
    const int rsw = (fm & 7) * 8;               // read-side swizzle XOR (elems)

    f32x4 acc[8][4];
#pragma unroll
    for (int u = 0; u < 8; ++u)
#pragma unroll
        for (int v = 0; v < 4; ++v) acc[u][v] = (f32x4){0.f, 0.f, 0.f, 0.f};

    bf16x8 af[4][2];   // current M-half: 4 mt x 2 ksub
    bf16x8 bv[8][2];   // whole tile's B: 4 nt x 2 ksub (both halves kept)

    // prologue: stage tiles 0 (buf0) and 1 (buf1) fully, consumption order
    STAGE_A(0, 0, 0); STAGE_B(0, 0, 0); STAGE_B(1, 0, 0); STAGE_A(1, 0, 0);
    STAGE_A(0, 1, 1); STAGE_B(0, 1, 1); STAGE_B(1, 1, 1); STAGE_A(1, 1, 1);
    VMCNT8;   // tile 0's 8 loads drained; tile 1's 8 in flight
    BARR;

    for (int kt = 0; kt < 14; ++kt) {
        const int c = kt & 1;
        // ---- phase 1: quadrant (Mh0, Nh0) ----
        LOAD_A(0, c);
        LOAD_B(0, c);
        BARR;
        MFMA_Q(0, 0);
        BARR;
        // ---- phase 2: quadrant (Mh0, Nh1); stage (t+2) Ah0 over consumed Ah0 ----
        LOAD_B(1, c);
        STAGE_A(0, kt + 2, c);
        BARR;
        MFMA_Q(0, 1);
        BARR;
        // ---- phase 3: quadrant (Mh1, Nh1); stage (t+2) Bh0 over consumed Bh0 ----
        LOAD_A(1, c);
        STAGE_B(0, kt + 2, c);
        BARR;
        MFMA_Q(1, 1);
        BARR;
        // ---- phase 4: quadrant (Mh1, Nh0); stage (t+2) Bh1+Ah1; ONE counted wait ----
        STAGE_B(1, kt + 2, c);
        STAGE_A(1, kt + 2, c);
        VMCNT8;                 // drains tile t+1's 8; leaves tile t+2's 8 in flight
        BARR;
        MFMA_Q(1, 0);
        BARR;
    }

    // ---- kt = 14 (buf 0): no staging; drain tile 15's loads at phase 4 ----
    {
        LOAD_A(0, 0);
        LOAD_B(0, 0);
        BARR;
        MFMA_Q(0, 0);
        BARR;
        LOAD_B(1, 0);
        BARR;
        MFMA_Q(0, 1);
        BARR;
        LOAD_A(1, 0);
        BARR;
        MFMA_Q(1, 1);
        BARR;
        VMCNT0;                 // tile 15's buffer fully valid
        BARR;
        MFMA_Q(1, 0);
        BARR;
    }

    // ---- kt = 15 (buf 1): fully resident, no barriers needed ----
    {
        LOAD_A(0, 1);
        LOAD_B(0, 1);
        MFMA_Q(0, 0);
        LOAD_B(1, 1);
        MFMA_Q(0, 1);
        LOAD_A(1, 1);
        MFMA_Q(1, 1);
        MFMA_Q(1, 0);
    }

    // ---- C write ----
    const int rq = fg * 4;
    float* op = Ob + (long long)(tm * 256 + wr * 128 + rq) * 1024 + tn * 256 + wc * 64 + fm;
#pragma unroll
    for (int mi = 0; mi < 8; ++mi)
#pragma unroll
        for (int ni = 0; ni < 4; ++ni)
#pragma unroll
            for (int r = 0; r < 4; ++r)
                op[(long long)(mi * 16 + r) * 1024 + ni * 16] = acc[mi][ni][r];
}

// ---------------- stats + softmax ----------------
__global__ __launch_bounds__(256) void stats_kernel(const float* __restrict__ S, float* __restrict__ st) {
    int pg = blockIdx.x;
    const float* s = S + (long long)pg * 65536;
    float sum = 0.f, sq = 0.f;
    for (int i = threadIdx.x; i < 65536; i += 256) {
        float v = s[i];
        sum += v;
        sq += v * v;
    }
#pragma unroll
    for (int off = 32; off; off >>= 1) {
        sum += __shfl_down(sum, off);
        sq  += __shfl_down(sq,  off);
    }
    __shared__ float r1[4], r2[4];
    int w = threadIdx.x >> 6;
    if ((threadIdx.x & 63) == 0) { r1[w] = sum; r2[w] = sq; }
    __syncthreads();
    if (threadIdx.x == 0) {
        float ts = r1[0] + r1[1] + r1[2] + r1[3];
        float tq = r2[0] + r2[1] + r2[2] + r2[3];
        float mean = ts * (1.0f / 65536.0f);
        float var = tq * (1.0f / 65536.0f) - mean * mean;
        st[pg * 2 + 0] = mean;
        st[pg * 2 + 1] = rsqrtf(var + 1e-5f);
    }
}

__global__ __launch_bounds__(256) void softmax_kernel(const float* __restrict__ S,
                                                      const float* __restrict__ st,
                                                      __bf16* __restrict__ p_bf) {
    int pg = blockIdx.y;
    int c = blockIdx.x;
    float mean = st[pg * 2 + 0], rstd = st[pg * 2 + 1];
    const float* row = S + (long long)pg * 65536 + c * 256;
    int t = threadIdx.x;
    float x = (row[t] - mean) * rstd;
    float m = x;
#pragma unroll
    for (int off = 32; off; off >>= 1) m = fmaxf(m, __shfl_down(m, off));
    __shared__ float r1[4], r2[4];
    int w = t >> 6;
    if ((t & 63) == 0) r1[w] = m;
    __syncthreads();
    m = fmaxf(fmaxf(r1[0], r1[1]), fmaxf(r1[2], r1[3]));
    float e = expf(x - m);
    float ssum = e;
#pragma unroll
    for (int off = 32; off; off >>= 1) ssum += __shfl_down(ssum, off);
    if ((t & 63) == 0) r2[w] = ssum;
    __syncthreads();
    ssum = r2[0] + r2[1] + r2[2] + r2[3];
    p_bf[(long long)pg * 65536 + c * 256 + t] = (__bf16)(e / ssum);
}

extern "C" void kernel_launch(void* const* d_in, const int* in_sizes, int n_in,
                              void* d_out, int out_size, void* d_ws, size_t ws_size,
                              hipStream_t stream) {
    const float* emb1     = (const float*)d_in[0];
    const float* emb_all  = (const float*)d_in[1];
    const float* embd1    = (const float*)d_in[2];
    const float* emb_alld = (const float*)d_in[3];
    const float* Wq    = (const float*)d_in[4];
    const float* Wqd   = (const float*)d_in[5];
    const float* Wk0   = (const float*)d_in[6];
    const float* Wv0   = (const float*)d_in[7];
    const float* Wkd0  = (const float*)d_in[8];
    const float* Wvd0  = (const float*)d_in[9];
    const float* Wout  = (const float*)d_in[10];
    const float* Woutd = (const float*)d_in[11];
    float* out = (float*)d_out;

    float* ws = (float*)d_ws;
    float*  Gpart   = ws;                             // 8,388,608 fl (dead after reduce_g)
    __bf16* Mb_bf   = (__bf16*)ws;                    // 8,388,608 bf16 (aliases Gpart)
    __bf16* X_bf    = (__bf16*)(ws + 8388608);        // 33,554,432 bf16 [emb_all | emb_alld]
    __bf16* GT_bf   = (__bf16*)(ws + 25165824);       // 2,097,152 bf16
    __bf16* T_bf    = (__bf16*)(ws + 26214400);       // 2,097,152 bf16
    float*  S       = ws + 27262976;                  // 2,097,152 fp32
    __bf16* p_bf    = (__bf16*)(ws + 29360128);       // 2,097,152 bf16
    __bf16* PT_bf   = (__bf16*)(ws + 30408704);       // 2,097,152 bf16
    __bf16* Wq_bf   = (__bf16*)(ws + 31457280);       // 524,288 bf16
    __bf16* Wk_bf   = (__bf16*)(ws + 31719424);       // 131,072 bf16
    __bf16* WvT_bf  = (__bf16*)(ws + 31784960);       // 131,072 bf16
    __bf16* WoutR_bf= (__bf16*)(ws + 31850496);       // 2,097,152 bf16
    float*  st      = ws + 32899072;                  // 64 fl  -> total ~131.6 MB

    dim3 blk(256);

    // prep
    prep_x<<<dim3(16384, 2), blk, 0, stream>>>(emb_all, emb_alld, X_bf);
    prep_w<<<11264, blk, 0, stream>>>(Wq, Wqd, Wk0, Wv0, Wkd0, Wvd0, Wout, Woutd,
                                      Wq_bf, Wk_bf, WvT_bf, WoutR_bf);

    // GT = Xm^T @ Xn (split-K x4) + reduce->bf16
    gram_mfma<<<dim3(4, 4, 32), blk, 0, stream>>>(emb1, emb_all, embd1, emb_alld, Gpart);
    reduce_g<<<2048, blk, 0, stream>>>(Gpart, GT_bf);

    // T = Wq_h @ G   (A=Wq_bf, B=GT)
    mfma_nt<__bf16><<<dim3(16, 32), blk, 0, stream>>>(
        Wq_bf, GT_bf, T_bf, 4, 256,
        262144, 0, 65536,  1048576, 262144, 65536,  1048576, 262144, 65536, 256, 1.0f);
    // S = scale * T @ Wk'^T
    mfma_nt<float><<<dim3(16, 32), blk, 0, stream>>>(
        T_bf, Wk_bf, S, 4, 256,
        1048576, 262144, 65536,  65536, 0, 0,  1048576, 262144, 65536, 256, 0.03125f);

    stats_kernel<<<32, blk, 0, stream>>>(S, st);
    softmax_kernel<<<dim3(256, 32), blk, 0, stream>>>(S, st, p_bf);

    // PT = WvT @ p^T
    mfma_nt<__bf16><<<dim3(16, 32), blk, 0, stream>>>(
        WvT_bf, p_bf, PT_bf, 4, 256,
        65536, 0, 0,  1048576, 262144, 65536,  1048576, 262144, 65536, 256, 1.0f);
    // Mb = WoutR @ PT^T   (M=1024)
    mfma_nt<__bf16><<<dim3(64, 32), blk, 0, stream>>>(
        WoutR_bf, PT_bf, Mb_bf, 16, 256,
        1048576, 0, 262144,  1048576, 262144, 65536,  4194304, 1048576, 256, 1024, 1.0f);

    // O = X @ Mb^T  (256x256 8-wave, deep-pipelined, T2 swizzle, one vmcnt/tile)
    obig8<<<dim3(512), dim3(512), 0, stream>>>(X_bf, Mb_bf, out);
}

// Round 4
// 507.507 us; speedup vs baseline: 1.2287x; 1.1190x over previous
//
#include <hip/hip_runtime.h>
#include <math.h>

// B=4, N=4096, C=1024, KV=1024, H=4, Ch=Kh=256
// z = (path<<4) | (b<<2) | h  for 32-group stages.
// path0 (O1): Xm=emb_alld, Xn=emb1, Wq, Wkd0, Wvd0, Wout, obig X=emb_alld
// path1 (Od1): Xm=emb_all, Xn=embd1, Wqd, Wk0, Wv0, Woutd, obig X=emb_all
// Chain: GT = Xm^T@Xn (per z) -> T = Wq@ (GT as B) -> S = T@Wk^T (*1/32)
//        p = softmax(instnorm(S)) -> PT = WvT@p^T -> Mb = WoutR@PT^T -> O = X@Mb^T

#define PITCH 40

typedef __bf16 bf16x4 __attribute__((ext_vector_type(4)));
typedef __bf16 bf16x8 __attribute__((ext_vector_type(8)));
typedef float f32x4 __attribute__((ext_vector_type(4)));

__device__ inline void gl2lds16(const void* g, void* l) {
    __builtin_amdgcn_global_load_lds(
        (const __attribute__((address_space(1))) unsigned int*)g,
        (__attribute__((address_space(3))) unsigned int*)l, 16, 0, 0);
}

// ---------------- prep: X fp32 -> bf16 ----------------
__global__ __launch_bounds__(256) void prep_x(const float* __restrict__ emb_all,
                                              const float* __restrict__ emb_alld,
                                              __bf16* __restrict__ Xb) {
    const float* src = blockIdx.y ? emb_alld : emb_all;
    __bf16* dst = Xb + (long long)blockIdx.y * 16777216;
    long long i4 = (long long)blockIdx.x * 256 + threadIdx.x;
    float4 v = *(const float4*)&src[i4 * 4];
    bf16x4 o = {(__bf16)v.x, (__bf16)v.y, (__bf16)v.z, (__bf16)v.w};
    *(bf16x4*)&dst[i4 * 4] = o;
}

// ---------------- prep: weights -> bf16 (+transpose/gather) ----------------
__global__ __launch_bounds__(256) void prep_w(
    const float* __restrict__ Wq, const float* __restrict__ Wqd,
    const float* __restrict__ Wk0, const float* __restrict__ Wv0,
    const float* __restrict__ Wkd0, const float* __restrict__ Wvd0,
    const float* __restrict__ Wout, const float* __restrict__ Woutd,
    __bf16* __restrict__ Wq_bf, __bf16* __restrict__ Wk_bf,
    __bf16* __restrict__ WvT_bf, __bf16* __restrict__ WoutR_bf)
{
    int id = blockIdx.x * 256 + threadIdx.x;
    if (id < 524288) {
        Wq_bf[id] = (__bf16)(id < 262144 ? Wq[id] : Wqd[id - 262144]);
    } else if (id < 655360) {
        int j = id - 524288;
        Wk_bf[j] = (__bf16)(j < 65536 ? Wkd0[j] : Wk0[j - 65536]);
    } else if (id < 786432) {
        int j = id - 655360;
        int p = j >> 16, r = (j >> 8) & 255, c2 = j & 255;
        const float* s = p ? Wv0 : Wvd0;
        WvT_bf[j] = (__bf16)s[c2 * 256 + r];   // WvT[m][k'] = Wv'[k'][m]
    } else if (id < 2883584) {
        int j = id - 786432;
        int p = j >> 20; int rem = j & 1048575; int h = rem >> 18; int oc = rem & 262143;
        int o = oc >> 8, c = oc & 255;
        const float* s = p ? Woutd : Wout;
        WoutR_bf[j] = (__bf16)s[o * 1024 + c * 4 + h];
    }
}

// ---------------- gram: GT partials = Xm^T @ Xn (fp32 in, split-K x4) ------------
// Streaming-optimized: one-step register prefetch, double-buffered LDS, ONE raw
// barrier per 32-K-step that waits lgkmcnt(0) only (global prefetch loads are
// NEVER drained by a barrier -> HBM latency stays hidden). Race-free with one
// barrier/step: each wave's ds_reads of step s-1 are lgkm-consumed by its MFMAs
// before it reaches barrier s, so step s+1's writes (other buffer) and step
// s+2's writes (same buffer) never overlap live reads.
__global__ __launch_bounds__(256, 2) void gram_mfma(
    const float* __restrict__ emb1, const float* __restrict__ emb_all,
    const float* __restrict__ embd1, const float* __restrict__ emb_alld,
    float* __restrict__ Gpart)
{
    __shared__ __bf16 As[2][128 * PITCH];
    __shared__ __bf16 Bs[2][128 * PITCH];

    const int z = blockIdx.z;
    const int path = z >> 4, bh = z & 15;
    const int b = bh >> 2, h = bh & 3;
    const float* Xm = (path == 0 ? emb_alld : emb_all) + (long long)b * 4194304 + h * 256;
    const float* Xn = (path == 0 ? emb1     : embd1)   + (long long)b * 4194304 + h * 256;

    const int i0 = (blockIdx.x >> 1) * 128;
    const int j0 = (blockIdx.x & 1) * 128;
    const int kb0 = blockIdx.y * 1024;

    const int t = threadIdx.x;
    const int q  = t & 7;        // k-row group (rows q*4 .. q*4+3 within step)
    const int i4 = t >> 3;       // col group (cols i4*4 .. i4*4+3)
    const int lane = t & 63;
    const int wave = t >> 6;
    const int wr = (wave >> 1) * 64, wc = (wave & 1) * 64;
    const int fm = lane & 15, fg = lane >> 4;

    f32x4 acc[4][4];
#pragma unroll
    for (int u = 0; u < 4; ++u)
#pragma unroll
        for (int v = 0; v < 4; ++v) acc[u][v] = (f32x4){0.f, 0.f, 0.f, 0.f};

    const float* pa = Xm + (long long)(kb0 + q * 4) * 1024 + i0 + i4 * 4;
    const float* pb = Xn + (long long)(kb0 + q * 4) * 1024 + j0 + i4 * 4;

    float4 vaA[4], vbA[4], vaB[4], vbB[4];
    // preload step 0 into set A
#pragma unroll
    for (int r = 0; r < 4; ++r) {
        vaA[r] = *(const float4*)(pa + (long long)r * 1024);
        vbA[r] = *(const float4*)(pb + (long long)r * 1024);
    }

#define GRAM_STEP(CURA, CURB, NXTA, NXTB, BUF, SOFF, GUARD)                         \
    do {                                                                            \
        if (GUARD) {                                                                \
            const float* qa = pa + (long long)(SOFF) * 32768;                       \
            const float* qb = pb + (long long)(SOFF) * 32768;                       \
            _Pragma("unroll")                                                       \
            for (int r = 0; r < 4; ++r) {                                           \
                NXTA[r] = *(const float4*)(qa + (long long)r * 1024);               \
                NXTB[r] = *(const float4*)(qb + (long long)r * 1024);               \
            }                                                                       \
        }                                                                           \
        _Pragma("unroll")                                                           \
        for (int cc = 0; cc < 4; ++cc) {                                            \
            bf16x4 wa, wb;                                                          \
            _Pragma("unroll")                                                       \
            for (int r = 0; r < 4; ++r) {                                           \
                wa[r] = (__bf16)(((const float*)&CURA[r])[cc]);                     \
                wb[r] = (__bf16)(((const float*)&CURB[r])[cc]);                     \
            }                                                                       \
            *(bf16x4*)&As[BUF][(i4 * 4 + cc) * PITCH + q * 4] = wa;                 \
            *(bf16x4*)&Bs[BUF][(i4 * 4 + cc) * PITCH + q * 4] = wb;                 \
        }                                                                           \
        asm volatile("s_waitcnt lgkmcnt(0)\ns_barrier" ::: "memory");               \
        bf16x8 af[4], bfv[4];                                                       \
        _Pragma("unroll")                                                           \
        for (int mt = 0; mt < 4; ++mt)                                              \
            af[mt] = *(const bf16x8*)&As[BUF][(wr + mt * 16 + fm) * PITCH + fg * 8];\
        _Pragma("unroll")                                                           \
        for (int nt = 0; nt < 4; ++nt)                                              \
            bfv[nt] = *(const bf16x8*)&Bs[BUF][(wc + nt * 16 + fm) * PITCH + fg * 8];\
        _Pragma("unroll")                                                           \
        for (int mt = 0; mt < 4; ++mt)                                              \
            _Pragma("unroll")                                                       \
            for (int nt = 0; nt < 4; ++nt)                                          \
                acc[mt][nt] = __builtin_amdgcn_mfma_f32_16x16x32_bf16(              \
                    af[mt], bfv[nt], acc[mt][nt], 0, 0, 0);                         \
    } while (0)

    for (int s = 0; s < 32; s += 2) {
        GRAM_STEP(vaA, vbA, vaB, vbB, 0, s + 1, true);          // even step s
        GRAM_STEP(vaB, vbB, vaA, vbA, 1, s + 2, (s < 30));      // odd step s+1
    }
#undef GRAM_STEP

    float* Gp = Gpart + ((long long)blockIdx.y * 32 + z) * 65536;
    const int col = lane & 15, rq = (lane >> 4) * 4;
#pragma unroll
    for (int mt = 0; mt < 4; ++mt)
#pragma unroll
        for (int nt = 0; nt < 4; ++nt)
#pragma unroll
            for (int r = 0; r < 4; ++r)
                Gp[(i0 + wr + mt * 16 + rq + r) * 256 + (j0 + wc + nt * 16 + col)] = acc[mt][nt][r];
}

__global__ __launch_bounds__(256) void reduce_g(const float* __restrict__ Gpart, __bf16* __restrict__ GT) {
    long long idx4 = (long long)blockIdx.x * 256 + threadIdx.x;   // < 524288
    float4 a = *(const float4*)&Gpart[idx4 * 4];
    float4 b = *(const float4*)&Gpart[2097152 + idx4 * 4];
    float4 c = *(const float4*)&Gpart[4194304 + idx4 * 4];
    float4 d = *(const float4*)&Gpart[6291456 + idx4 * 4];
    bf16x4 o;
    o[0] = (__bf16)(a.x + b.x + c.x + d.x);
    o[1] = (__bf16)(a.y + b.y + c.y + d.y);
    o[2] = (__bf16)(a.z + b.z + c.z + d.z);
    o[3] = (__bf16)(a.w + b.w + c.w + d.w);
    *(bf16x4*)&GT[idx4 * 4] = o;
}

// ---------------- generic NT MFMA: C[z] = alpha * A[z] @ B[z]^T ----------------
template <typename CT>
__global__ __launch_bounds__(256) void mfma_nt(
    const __bf16* __restrict__ A, const __bf16* __restrict__ B, CT* __restrict__ C,
    int mtiles, int K,
    long long a1, long long a2, long long a3,
    long long b1, long long b2, long long b3,
    long long c1, long long c2, long long c3,
    int cpitch, float alpha)
{
    __shared__ __bf16 As[64 * 32];
    __shared__ __bf16 Bs[64 * 32];
    const int z = blockIdx.y;
    const __bf16* Az = A + (long long)(z >> 4) * a1 + (long long)((z >> 2) & 3) * a2 + (long long)(z & 3) * a3;
    const __bf16* Bz = B + (long long)(z >> 4) * b1 + (long long)((z >> 2) & 3) * b2 + (long long)(z & 3) * b3;
    CT* Cz = C + (long long)(z >> 4) * c1 + (long long)((z >> 2) & 3) * c2 + (long long)(z & 3) * c3;

    const int tm = blockIdx.x % mtiles, tn = blockIdx.x / mtiles;
    const int t = threadIdx.x;
    const int lane = t & 63, wave = t >> 6;
    const int row = t >> 2, ch = t & 3;
    const int fm = lane & 15, fg = lane >> 4;

    const __bf16* ga = Az + (long long)(tm * 64 + row) * K + ch * 8;
    const __bf16* gb = Bz + (long long)(tn * 64 + row) * K + ch * 8;
    __bf16* la = &As[t * 8];
    __bf16* lb = &Bs[t * 8];

    f32x4 acc[4];
#pragma unroll
    for (int u = 0; u < 4; ++u) acc[u] = (f32x4){0.f, 0.f, 0.f, 0.f};

    for (int kb = 0; kb < K; kb += 32) {
        __syncthreads();
        gl2lds16(ga + kb, la);
        gl2lds16(gb + kb, lb);
        __syncthreads();
        bf16x8 bv = *(const bf16x8*)&Bs[(wave * 16 + fm) * 32 + fg * 8];
#pragma unroll
        for (int mt = 0; mt < 4; ++mt) {
            bf16x8 av = *(const bf16x8*)&As[(mt * 16 + fm) * 32 + fg * 8];
            acc[mt] = __builtin_amdgcn_mfma_f32_16x16x32_bf16(av, bv, acc[mt], 0, 0, 0);
        }
    }

    const int colc = tn * 64 + wave * 16 + fm;
    const int rq = fg * 4;
#pragma unroll
    for (int mt = 0; mt < 4; ++mt)
#pragma unroll
        for (int r = 0; r < 4; ++r) {
            int rowc = tm * 64 + mt * 16 + rq + r;
            Cz[(long long)rowc * cpitch + colc] = (CT)(acc[mt][r] * alpha);
        }
}

// ---------------- obig: O = X @ Mb^T, 256x256 tile, 8 waves, BK=64 ----------------
// 4 phases per K-tile (one C-quadrant each), T2 swizzle, T5 setprio.
// Deep pipeline: prologue stages tiles 0+1; during tile t, stage tile t+2 into
// the *current* buffer over quadrants already consumed this tile. ONE vmcnt(8)
// per K-tile at phase 4 validates tile t+1's whole buffer.

#define VMCNT8 asm volatile("s_waitcnt vmcnt(8)" ::: "memory")
#define VMCNT0 asm volatile("s_waitcnt vmcnt(0)" ::: "memory")
#define BARR   asm volatile("s_barrier" ::: "memory")

#define STAGE_A(h, kt, c) do { \
    _Pragma("unroll") \
    for (int o = 0; o < 2; ++o) { \
        int rl = (h) * 64 + o * 128 + stg_row; \
        gl2lds16(Xa + (long long)rl * 1024 + (kt) * 64 + stg_col, \
                 &lds[(c) * 32768 + rl * 64 + lin_col]); \
    } \
} while (0)

#define STAGE_B(h, kt, c) do { \
    _Pragma("unroll") \
    for (int o = 0; o < 2; ++o) { \
        int rl = o * 128 + (h) * 32 + (stg_row & 31) + ((stg_row & 32) << 1); \
        gl2lds16(Bb + (long long)rl * 1024 + (kt) * 64 + stg_col, \
                 &lds[(c) * 32768 + 16384 + rl * 64 + lin_col]); \
    } \
} while (0)

#define LOAD_A(hm, c) do { \
    _Pragma("unroll") \
    for (int mt = 0; mt < 4; ++mt) { \
        const __bf16* p = &lds[(c) * 32768 + (wr * 128 + (hm) * 64 + mt * 16 + fm) * 64]; \
        af[mt][0] = *(const bf16x8*)&p[(fg * 8) ^ rsw]; \
        af[mt][1] = *(const bf16x8*)&p[(32 + fg * 8) ^ rsw]; \
    } \
} while (0)

#define LOAD_B(hn, c) do { \
    _Pragma("unroll") \
    for (int nt = 0; nt < 2; ++nt) { \
        const __bf16* p = &lds[(c) * 32768 + 16384 + (wc * 64 + (hn) * 32 + nt * 16 + fm) * 64]; \
        bv[(hn) * 2 + nt][0] = *(const bf16x8*)&p[(fg * 8) ^ rsw]; \
        bv[(hn) * 2 + nt][1] = *(const bf16x8*)&p[(32 + fg * 8) ^ rsw]; \
    } \
} while (0)

#define MFMA_Q(hm, hn) do { \
    __builtin_amdgcn_s_setprio(1); \
    _Pragma("unroll") \
    for (int mt = 0; mt < 4; ++mt) \
        _Pragma("unroll") \
        for (int nt = 0; nt < 2; ++nt) { \
            acc[(hm) * 4 + mt][(hn) * 2 + nt] = __builtin_amdgcn_mfma_f32_16x16x32_bf16( \
                af[mt][0], bv[(hn) * 2 + nt][0], acc[(hm) * 4 + mt][(hn) * 2 + nt], 0, 0, 0); \
            acc[(hm) * 4 + mt][(hn) * 2 + nt] = __builtin_amdgcn_mfma_f32_16x16x32_bf16( \
                af[mt][1], bv[(hn) * 2 + nt][1], acc[(hm) * 4 + mt][(hn) * 2 + nt], 0, 0, 0); \
        } \
    __builtin_amdgcn_s_setprio(0); \
} while (0)

__global__ __launch_bounds__(512, 2) void obig8(
    const __bf16* __restrict__ Xall, const __bf16* __restrict__ Mb, float* __restrict__ out)
{
    __shared__ __bf16 lds[65536];   // [buf0: A 32KB | B 32KB][buf1: A 32KB | B 32KB]

    const int id = blockIdx.x;                  // 0..511
    const int wg = (id & 7) * 64 + (id >> 3);   // bijective XCD swizzle: one z per XCD
    const int z = wg >> 6;                      // 0..7
    const int tile = wg & 63;
    const int tm = tile & 15, tn = tile >> 4;   // 16 m-tiles x 4 n-tiles
    const int path = z >> 2, b = z & 3;

    const __bf16* Xa = Xall + (path == 0 ? 16777216LL : 0LL)
                     + (long long)b * 4194304 + (long long)tm * 262144;
    const __bf16* Bb = Mb + (long long)path * 4194304 + (long long)b * 1048576
                     + (long long)tn * 262144;
    float* Ob = out + (long long)path * 16777216 + (long long)b * 4194304;

    const int t = threadIdx.x;
    const int lane = t & 63, wave = t >> 6;     // 8 waves: 2M x 4N
    const int wr = wave >> 2, wc = wave & 3;
    const int fm = lane & 15, fg = lane >> 4;
    const int stg_row = t >> 3;                 // 0..63
    const int lin_col = (t & 7) * 8;            // linear LDS dest col (elems)
    const int stg_col = ((t & 7) ^ (stg_row & 7)) * 8;  // inverse-swizzled global col
    const int rsw = (fm & 7) * 8;               // read-side swizzle XOR (elems)

    f32x4 acc[8][4];
#pragma unroll
    for (int u = 0; u < 8; ++u)
#pragma unroll
        for (int v = 0; v < 4; ++v) acc[u][v] = (f32x4){0.f, 0.f, 0.f, 0.f};

    bf16x8 af[4][2];   // current M-half: 4 mt x 2 ksub
    bf16x8 bv[8][2];   // whole tile's B: 4 nt x 2 ksub (both halves kept)

    // prologue: stage tiles 0 (buf0) and 1 (buf1) fully, consumption order
    STAGE_A(0, 0, 0); STAGE_B(0, 0, 0); STAGE_B(1, 0, 0); STAGE_A(1, 0, 0);
    STAGE_A(0, 1, 1); STAGE_B(0, 1, 1); STAGE_B(1, 1, 1); STAGE_A(1, 1, 1);
    VMCNT8;   // tile 0's 8 loads drained; tile 1's 8 in flight
    BARR;

    for (int kt = 0; kt < 14; ++kt) {
        const int c = kt & 1;
        // ---- phase 1: quadrant (Mh0, Nh0) ----
        LOAD_A(0, c);
        LOAD_B(0, c);
        BARR;
        MFMA_Q(0, 0);
        BARR;
        // ---- phase 2: quadrant (Mh0, Nh1); stage (t+2) Ah0 over consumed Ah0 ----
        LOAD_B(1, c);
        STAGE_A(0, kt + 2, c);
        BARR;
        MFMA_Q(0, 1);
        BARR;
        // ---- phase 3: quadrant (Mh1, Nh1); stage (t+2) Bh0 over consumed Bh0 ----
        LOAD_A(1, c);
        STAGE_B(0, kt + 2, c);
        BARR;
        MFMA_Q(1, 1);
        BARR;
        // ---- phase 4: quadrant (Mh1, Nh0); stage (t+2) Bh1+Ah1; ONE counted wait ----
        STAGE_B(1, kt + 2, c);
        STAGE_A(1, kt + 2, c);
        VMCNT8;                 // drains tile t+1's 8; leaves tile t+2's 8 in flight
        BARR;
        MFMA_Q(1, 0);
        BARR;
    }

    // ---- kt = 14 (buf 0): no staging; drain tile 15's loads at phase 4 ----
    {
        LOAD_A(0, 0);
        LOAD_B(0, 0);
        BARR;
        MFMA_Q(0, 0);
        BARR;
        LOAD_B(1, 0);
        BARR;
        MFMA_Q(0, 1);
        BARR;
        LOAD_A(1, 0);
        BARR;
        MFMA_Q(1, 1);
        BARR;
        VMCNT0;                 // tile 15's buffer fully valid
        BARR;
        MFMA_Q(1, 0);
        BARR;
    }

    // ---- kt = 15 (buf 1): fully resident, no barriers needed ----
    {
        LOAD_A(0, 1);
        LOAD_B(0, 1);
        MFMA_Q(0, 0);
        LOAD_B(1, 1);
        MFMA_Q(0, 1);
        LOAD_A(1, 1);
        MFMA_Q(1, 1);
        MFMA_Q(1, 0);
    }

    // ---- C write ----
    const int rq = fg * 4;
    float* op = Ob + (long long)(tm * 256 + wr * 128 + rq) * 1024 + tn * 256 + wc * 64 + fm;
#pragma unroll
    for (int mi = 0; mi < 8; ++mi)
#pragma unroll
        for (int ni = 0; ni < 4; ++ni)
#pragma unroll
            for (int r = 0; r < 4; ++r)
                op[(long long)(mi * 16 + r) * 1024 + ni * 16] = acc[mi][ni][r];
}

// ---------------- stats (partial) + softmax ----------------
// stats1: 8 chunk-blocks per plane-group -> partial (sum, sumsq) pairs.
__global__ __launch_bounds__(256) void stats1_kernel(const float* __restrict__ S,
                                                     float* __restrict__ pstat) {
    const int ch = blockIdx.x, pg = blockIdx.y;
    const float* s = S + (long long)pg * 65536 + ch * 8192;
    const int t = threadIdx.x;
    float sum = 0.f, sq = 0.f;
#pragma unroll
    for (int i = 0; i < 8; ++i) {
        float4 v = *(const float4*)&s[(i * 256 + t) * 4];
        sum += v.x + v.y + v.z + v.w;
        sq += v.x * v.x + v.y * v.y + v.z * v.z + v.w * v.w;
    }
#pragma unroll
    for (int off = 32; off; off >>= 1) {
        sum += __shfl_down(sum, off);
        sq  += __shfl_down(sq,  off);
    }
    __shared__ float r1[4], r2[4];
    int w = t >> 6;
    if ((t & 63) == 0) { r1[w] = sum; r2[w] = sq; }
    __syncthreads();
    if (t == 0) {
        pstat[(pg * 8 + ch) * 2 + 0] = r1[0] + r1[1] + r1[2] + r1[3];
        pstat[(pg * 8 + ch) * 2 + 1] = r2[0] + r2[1] + r2[2] + r2[3];
    }
}

// softmax: 4 rows per block, one wave per row, no __syncthreads.
__global__ __launch_bounds__(256) void softmax_kernel(const float* __restrict__ S,
                                                      const float* __restrict__ pstat,
                                                      __bf16* __restrict__ p_bf) {
    const int pg = blockIdx.y;
    float ts = 0.f, tq = 0.f;
#pragma unroll
    for (int i = 0; i < 8; ++i) {
        ts += pstat[(pg * 8 + i) * 2 + 0];
        tq += pstat[(pg * 8 + i) * 2 + 1];
    }
    const float mean = ts * (1.0f / 65536.0f);
    const float rstd = rsqrtf(tq * (1.0f / 65536.0f) - mean * mean + 1e-5f);

    const int wave = threadIdx.x >> 6, lane = threadIdx.x & 63;
    const int c = blockIdx.x * 4 + wave;
    const float* row = S + (long long)pg * 65536 + c * 256;
    float4 v = *(const float4*)&row[lane * 4];
    float x0 = (v.x - mean) * rstd, x1 = (v.y - mean) * rstd;
    float x2 = (v.z - mean) * rstd, x3 = (v.w - mean) * rstd;
    float m = fmaxf(fmaxf(x0, x1), fmaxf(x2, x3));
#pragma unroll
    for (int off = 32; off; off >>= 1) m = fmaxf(m, __shfl_xor(m, off));
    float e0 = expf(x0 - m), e1 = expf(x1 - m), e2 = expf(x2 - m), e3 = expf(x3 - m);
    float ssum = e0 + e1 + e2 + e3;
#pragma unroll
    for (int off = 32; off; off >>= 1) ssum += __shfl_xor(ssum, off);
    float inv = 1.0f / ssum;
    bf16x4 o = {(__bf16)(e0 * inv), (__bf16)(e1 * inv), (__bf16)(e2 * inv), (__bf16)(e3 * inv)};
    *(bf16x4*)&p_bf[(long long)pg * 65536 + c * 256 + lane * 4] = o;
}

extern "C" void kernel_launch(void* const* d_in, const int* in_sizes, int n_in,
                              void* d_out, int out_size, void* d_ws, size_t ws_size,
                              hipStream_t stream) {
    const float* emb1     = (const float*)d_in[0];
    const float* emb_all  = (const float*)d_in[1];
    const float* embd1    = (const float*)d_in[2];
    const float* emb_alld = (const float*)d_in[3];
    const float* Wq    = (const float*)d_in[4];
    const float* Wqd   = (const float*)d_in[5];
    const float* Wk0   = (const float*)d_in[6];
    const float* Wv0   = (const float*)d_in[7];
    const float* Wkd0  = (const float*)d_in[8];
    const float* Wvd0  = (const float*)d_in[9];
    const float* Wout  = (const float*)d_in[10];
    const float* Woutd = (const float*)d_in[11];
    float* out = (float*)d_out;

    float* ws = (float*)d_ws;
    float*  Gpart   = ws;                             // 8,388,608 fl (dead after reduce_g)
    __bf16* Mb_bf   = (__bf16*)ws;                    // 8,388,608 bf16 (aliases Gpart)
    __bf16* X_bf    = (__bf16*)(ws + 8388608);        // 33,554,432 bf16 [emb_all | emb_alld]
    __bf16* GT_bf   = (__bf16*)(ws + 25165824);       // 2,097,152 bf16
    __bf16* T_bf    = (__bf16*)(ws + 26214400);       // 2,097,152 bf16
    float*  S       = ws + 27262976;                  // 2,097,152 fp32
    __bf16* p_bf    = (__bf16*)(ws + 29360128);       // 2,097,152 bf16
    __bf16* PT_bf   = (__bf16*)(ws + 30408704);       // 2,097,152 bf16
    __bf16* Wq_bf   = (__bf16*)(ws + 31457280);       // 524,288 bf16
    __bf16* Wk_bf   = (__bf16*)(ws + 31719424);       // 131,072 bf16
    __bf16* WvT_bf  = (__bf16*)(ws + 31784960);       // 131,072 bf16
    __bf16* WoutR_bf= (__bf16*)(ws + 31850496);       // 2,097,152 bf16
    float*  st      = ws + 32899072;                  // 512 fl partials

    dim3 blk(256);

    // prep
    prep_x<<<dim3(16384, 2), blk, 0, stream>>>(emb_all, emb_alld, X_bf);
    prep_w<<<11264, blk, 0, stream>>>(Wq, Wqd, Wk0, Wv0, Wkd0, Wvd0, Wout, Woutd,
                                      Wq_bf, Wk_bf, WvT_bf, WoutR_bf);

    // GT = Xm^T @ Xn (split-K x4) + reduce->bf16
    gram_mfma<<<dim3(4, 4, 32), blk, 0, stream>>>(emb1, emb_all, embd1, emb_alld, Gpart);
    reduce_g<<<2048, blk, 0, stream>>>(Gpart, GT_bf);

    // T = Wq_h @ G   (A=Wq_bf, B=GT)
    mfma_nt<__bf16><<<dim3(16, 32), blk, 0, stream>>>(
        Wq_bf, GT_bf, T_bf, 4, 256,
        262144, 0, 65536,  1048576, 262144, 65536,  1048576, 262144, 65536, 256, 1.0f);
    // S = scale * T @ Wk'^T
    mfma_nt<float><<<dim3(16, 32), blk, 0, stream>>>(
        T_bf, Wk_bf, S, 4, 256,
        1048576, 262144, 65536,  65536, 0, 0,  1048576, 262144, 65536, 256, 0.03125f);

    stats1_kernel<<<dim3(8, 32), blk, 0, stream>>>(S, st);
    softmax_kernel<<<dim3(64, 32), blk, 0, stream>>>(S, st, p_bf);

    // PT = WvT @ p^T
    mfma_nt<__bf16><<<dim3(16, 32), blk, 0, stream>>>(
        WvT_bf, p_bf, PT_bf, 4, 256,
        65536, 0, 0,  1048576, 262144, 65536,  1048576, 262144, 65536, 256, 1.0f);
    // Mb = WoutR @ PT^T   (M=1024)
    mfma_nt<__bf16><<<dim3(64, 32), blk, 0, stream>>>(
        WoutR_bf, PT_bf, Mb_bf, 16, 256,
        1048576, 0, 262144,  1048576, 262144, 65536,  4194304, 1048576, 256, 1024, 1.0f);

    // O = X @ Mb^T  (256x256 8-wave, deep-pipelined, T2 swizzle, one vmcnt/tile)
    obig8<<<dim3(512), dim3(512), 0, stream>>>(X_bf, Mb_bf, out);
}

// Round 5
// 501.810 us; speedup vs baseline: 1.2426x; 1.0114x over previous
//
#include <hip/hip_runtime.h>
#include <math.h>

// B=4, N=4096, C=1024, KV=1024, H=4, Ch=Kh=256
// z = (path<<4) | (b<<2) | h  for 32-group stages.
// path0 (O1): Xm=emb_alld, Xn=emb1, Wq, Wkd0, Wvd0, Wout, obig X=emb_alld
// path1 (Od1): Xm=emb_all, Xn=embd1, Wqd, Wk0, Wv0, Woutd, obig X=emb_all
// Chain: GT = Xm^T@Xn (per z) -> T = Wq@ (GT as B) -> S = T@Wk^T (*1/32)
//        p = softmax(instnorm(S)) -> PT = WvT@p^T -> Mb = WoutR@PT^T -> O = X@Mb^T

#define PITCH 40

typedef __bf16 bf16x4 __attribute__((ext_vector_type(4)));
typedef __bf16 bf16x8 __attribute__((ext_vector_type(8)));
typedef float f32x4 __attribute__((ext_vector_type(4)));

__device__ inline void gl2lds16(const void* g, void* l) {
    __builtin_amdgcn_global_load_lds(
        (const __attribute__((address_space(1))) unsigned int*)g,
        (__attribute__((address_space(3))) unsigned int*)l, 16, 0, 0);
}

// ---------------- prep: X fp32 -> bf16 ----------------
__global__ __launch_bounds__(256) void prep_x(const float* __restrict__ emb_all,
                                              const float* __restrict__ emb_alld,
                                              __bf16* __restrict__ Xb) {
    const float* src = blockIdx.y ? emb_alld : emb_all;
    __bf16* dst = Xb + (long long)blockIdx.y * 16777216;
    long long i4 = (long long)blockIdx.x * 256 + threadIdx.x;
    float4 v = *(const float4*)&src[i4 * 4];
    bf16x4 o = {(__bf16)v.x, (__bf16)v.y, (__bf16)v.z, (__bf16)v.w};
    *(bf16x4*)&dst[i4 * 4] = o;
}

// ---------------- prep: weights -> bf16 (+transpose/gather) ----------------
__global__ __launch_bounds__(256) void prep_w(
    const float* __restrict__ Wq, const float* __restrict__ Wqd,
    const float* __restrict__ Wk0, const float* __restrict__ Wv0,
    const float* __restrict__ Wkd0, const float* __restrict__ Wvd0,
    const float* __restrict__ Wout, const float* __restrict__ Woutd,
    __bf16* __restrict__ Wq_bf, __bf16* __restrict__ Wk_bf,
    __bf16* __restrict__ WvT_bf, __bf16* __restrict__ WoutR_bf)
{
    int id = blockIdx.x * 256 + threadIdx.x;
    if (id < 524288) {
        Wq_bf[id] = (__bf16)(id < 262144 ? Wq[id] : Wqd[id - 262144]);
    } else if (id < 655360) {
        int j = id - 524288;
        Wk_bf[j] = (__bf16)(j < 65536 ? Wkd0[j] : Wk0[j - 65536]);
    } else if (id < 786432) {
        int j = id - 655360;
        int p = j >> 16, r = (j >> 8) & 255, c2 = j & 255;
        const float* s = p ? Wv0 : Wvd0;
        WvT_bf[j] = (__bf16)s[c2 * 256 + r];   // WvT[m][k'] = Wv'[k'][m]
    } else if (id < 2883584) {
        int j = id - 786432;
        int p = j >> 20; int rem = j & 1048575; int h = rem >> 18; int oc = rem & 262143;
        int o = oc >> 8, c = oc & 255;
        const float* s = p ? Woutd : Wout;
        WoutR_bf[j] = (__bf16)s[o * 1024 + c * 4 + h];
    }
}

// ---------------- gram: GT partials = Xm^T @ Xn (fp32 in, split-K x8) ------------
// 256x256 tile = FULL G per z per block -> every input byte read by EXACTLY ONE
// block (delivered bytes halved vs 128-tiles) and each k-row fetched as one
// contiguous 1KB span (coarser DRAM granule). 512 threads / 8 waves (2x4),
// 8x4 fragments per wave. Verified 1-barrier/step schedule: reg prefetch of
// step s+1 issued before cvt of step s; barrier waits lgkmcnt(0) only -> global
// loads never drained by a barrier. Race-free: each wave's ds_reads of step s
// are lgkm-consumed before it reaches barrier s+1; writes of step s+2 (same
// buffer) occur only after barrier s+1.
__global__ __launch_bounds__(512, 2) void gram_mfma(
    const float* __restrict__ emb1, const float* __restrict__ emb_all,
    const float* __restrict__ embd1, const float* __restrict__ emb_alld,
    float* __restrict__ Gpart)
{
    __shared__ __bf16 As[2][256 * PITCH];
    __shared__ __bf16 Bs[2][256 * PITCH];

    const int z = blockIdx.y;           // 0..31
    const int split = blockIdx.x;       // 0..7 (split-K)
    const int path = z >> 4, bh = z & 15;
    const int b = bh >> 2, h = bh & 3;
    const float* Xm = (path == 0 ? emb_alld : emb_all) + (long long)b * 4194304 + h * 256;
    const float* Xn = (path == 0 ? emb1     : embd1)   + (long long)b * 4194304 + h * 256;

    const int kb0 = split * 512;

    const int t = threadIdx.x;          // 0..511
    const int q  = t & 7;               // k sub-group (rows q*4..q*4+3 in step)
    const int i4 = t >> 3;              // 0..63 col group (4 cols)
    const int lane = t & 63;
    const int wave = t >> 6;            // 8 waves: 2M x 4N
    const int wr = wave >> 2, wc = wave & 3;
    const int fm = lane & 15, fg = lane >> 4;

    f32x4 acc[8][4];
#pragma unroll
    for (int u = 0; u < 8; ++u)
#pragma unroll
        for (int v = 0; v < 4; ++v) acc[u][v] = (f32x4){0.f, 0.f, 0.f, 0.f};

    const float* pa = Xm + (long long)(kb0 + q * 4) * 1024 + i4 * 4;
    const float* pb = Xn + (long long)(kb0 + q * 4) * 1024 + i4 * 4;

    float4 aA[4], bA[4], aB[4], bB[4];
    // preload step 0 into set A
#pragma unroll
    for (int r = 0; r < 4; ++r) {
        aA[r] = *(const float4*)(pa + (long long)r * 1024);
        bA[r] = *(const float4*)(pb + (long long)r * 1024);
    }

#define GRAM_STEP(CA, CB, NA, NB, BUF, SOFF, GUARD)                                 \
    do {                                                                            \
        if (GUARD) {                                                                \
            const float* qa = pa + (long long)(SOFF) * 32768;                       \
            const float* qb = pb + (long long)(SOFF) * 32768;                       \
            _Pragma("unroll")                                                       \
            for (int r = 0; r < 4; ++r) {                                           \
                NA[r] = *(const float4*)(qa + (long long)r * 1024);                 \
                NB[r] = *(const float4*)(qb + (long long)r * 1024);                 \
            }                                                                       \
        }                                                                           \
        _Pragma("unroll")                                                           \
        for (int cc = 0; cc < 4; ++cc) {                                            \
            bf16x4 wa, wb;                                                          \
            _Pragma("unroll")                                                       \
            for (int r = 0; r < 4; ++r) {                                           \
                wa[r] = (__bf16)(((const float*)&CA[r])[cc]);                       \
                wb[r] = (__bf16)(((const float*)&CB[r])[cc]);                       \
            }                                                                       \
            *(bf16x4*)&As[BUF][(i4 * 4 + cc) * PITCH + q * 4] = wa;                 \
            *(bf16x4*)&Bs[BUF][(i4 * 4 + cc) * PITCH + q * 4] = wb;                 \
        }                                                                           \
        asm volatile("s_waitcnt lgkmcnt(0)\ns_barrier" ::: "memory");               \
        bf16x8 bfv[4];                                                              \
        _Pragma("unroll")                                                           \
        for (int nt = 0; nt < 4; ++nt)                                              \
            bfv[nt] = *(const bf16x8*)&Bs[BUF][(wc * 64 + nt * 16 + fm) * PITCH + fg * 8]; \
        _Pragma("unroll")                                                           \
        for (int mt = 0; mt < 8; ++mt) {                                            \
            bf16x8 af = *(const bf16x8*)&As[BUF][(wr * 128 + mt * 16 + fm) * PITCH + fg * 8]; \
            _Pragma("unroll")                                                       \
            for (int nt = 0; nt < 4; ++nt)                                          \
                acc[mt][nt] = __builtin_amdgcn_mfma_f32_16x16x32_bf16(              \
                    af, bfv[nt], acc[mt][nt], 0, 0, 0);                             \
        }                                                                           \
    } while (0)

    for (int s = 0; s < 16; s += 2) {
        GRAM_STEP(aA, bA, aB, bB, 0, s + 1, true);          // even step s
        GRAM_STEP(aB, bB, aA, bA, 1, s + 2, (s < 14));      // odd step s+1
    }
#undef GRAM_STEP

    float* Gp = Gpart + ((long long)split * 32 + z) * 65536;
    const int rq = fg * 4;
#pragma unroll
    for (int mt = 0; mt < 8; ++mt)
#pragma unroll
        for (int nt = 0; nt < 4; ++nt)
#pragma unroll
            for (int r = 0; r < 4; ++r)
                Gp[(wr * 128 + mt * 16 + rq + r) * 256 + (wc * 64 + nt * 16 + fm)] = acc[mt][nt][r];
}

__global__ __launch_bounds__(256) void reduce_g(const float* __restrict__ Gpart, __bf16* __restrict__ GT) {
    long long idx4 = (long long)blockIdx.x * 256 + threadIdx.x;   // < 524288
    float4 s0 = *(const float4*)&Gpart[idx4 * 4];
    float4 s1 = *(const float4*)&Gpart[2097152 + idx4 * 4];
    float4 s2 = *(const float4*)&Gpart[4194304 + idx4 * 4];
    float4 s3 = *(const float4*)&Gpart[6291456 + idx4 * 4];
    float4 s4 = *(const float4*)&Gpart[8388608 + idx4 * 4];
    float4 s5 = *(const float4*)&Gpart[10485760 + idx4 * 4];
    float4 s6 = *(const float4*)&Gpart[12582912 + idx4 * 4];
    float4 s7 = *(const float4*)&Gpart[14680064 + idx4 * 4];
    bf16x4 o;
    o[0] = (__bf16)(((s0.x + s1.x) + (s2.x + s3.x)) + ((s4.x + s5.x) + (s6.x + s7.x)));
    o[1] = (__bf16)(((s0.y + s1.y) + (s2.y + s3.y)) + ((s4.y + s5.y) + (s6.y + s7.y)));
    o[2] = (__bf16)(((s0.z + s1.z) + (s2.z + s3.z)) + ((s4.z + s5.z) + (s6.z + s7.z)));
    o[3] = (__bf16)(((s0.w + s1.w) + (s2.w + s3.w)) + ((s4.w + s5.w) + (s6.w + s7.w)));
    *(bf16x4*)&GT[idx4 * 4] = o;
}

// ---------------- generic NT MFMA: C[z] = alpha * A[z] @ B[z]^T ----------------
template <typename CT>
__global__ __launch_bounds__(256) void mfma_nt(
    const __bf16* __restrict__ A, const __bf16* __restrict__ B, CT* __restrict__ C,
    int mtiles, int K,
    long long a1, long long a2, long long a3,
    long long b1, long long b2, long long b3,
    long long c1, long long c2, long long c3,
    int cpitch, float alpha)
{
    __shared__ __bf16 As[64 * 32];
    __shared__ __bf16 Bs[64 * 32];
    const int z = blockIdx.y;
    const __bf16* Az = A + (long long)(z >> 4) * a1 + (long long)((z >> 2) & 3) * a2 + (long long)(z & 3) * a3;
    const __bf16* Bz = B + (long long)(z >> 4) * b1 + (long long)((z >> 2) & 3) * b2 + (long long)(z & 3) * b3;
    CT* Cz = C + (long long)(z >> 4) * c1 + (long long)((z >> 2) & 3) * c2 + (long long)(z & 3) * c3;

    const int tm = blockIdx.x % mtiles, tn = blockIdx.x / mtiles;
    const int t = threadIdx.x;
    const int lane = t & 63, wave = t >> 6;
    const int row = t >> 2, ch = t & 3;
    const int fm = lane & 15, fg = lane >> 4;

    const __bf16* ga = Az + (long long)(tm * 64 + row) * K + ch * 8;
    const __bf16* gb = Bz + (long long)(tn * 64 + row) * K + ch * 8;
    __bf16* la = &As[t * 8];
    __bf16* lb = &Bs[t * 8];

    f32x4 acc[4];
#pragma unroll
    for (int u = 0; u < 4; ++u) acc[u] = (f32x4){0.f, 0.f, 0.f, 0.f};

    for (int kb = 0; kb < K; kb += 32) {
        __syncthreads();
        gl2lds16(ga + kb, la);
        gl2lds16(gb + kb, lb);
        __syncthreads();
        bf16x8 bv = *(const bf16x8*)&Bs[(wave * 16 + fm) * 32 + fg * 8];
#pragma unroll
        for (int mt = 0; mt < 4; ++mt) {
            bf16x8 av = *(const bf16x8*)&As[(mt * 16 + fm) * 32 + fg * 8];
            acc[mt] = __builtin_amdgcn_mfma_f32_16x16x32_bf16(av, bv, acc[mt], 0, 0, 0);
        }
    }

    const int colc = tn * 64 + wave * 16 + fm;
    const int rq = fg * 4;
#pragma unroll
    for (int mt = 0; mt < 4; ++mt)
#pragma unroll
        for (int r = 0; r < 4; ++r) {
            int rowc = tm * 64 + mt * 16 + rq + r;
            Cz[(long long)rowc * cpitch + colc] = (CT)(acc[mt][r] * alpha);
        }
}

// ---------------- obig: O = X @ Mb^T, 256x256 tile, 8 waves, BK=64 ----------------
// 4 phases per K-tile (one C-quadrant each), T2 swizzle, T5 setprio.
// Deep pipeline: prologue stages tiles 0+1; during tile t, stage tile t+2 into
// the *current* buffer over quadrants already consumed this tile. ONE vmcnt(8)
// per K-tile at phase 4 validates tile t+1's whole buffer.

#define VMCNT8 asm volatile("s_waitcnt vmcnt(8)" ::: "memory")
#define VMCNT0 asm volatile("s_waitcnt vmcnt(0)" ::: "memory")
#define BARR   asm volatile("s_barrier" ::: "memory")

#define STAGE_A(h, kt, c) do { \
    _Pragma("unroll") \
    for (int o = 0; o < 2; ++o) { \
        int rl = (h) * 64 + o * 128 + stg_row; \
        gl2lds16(Xa + (long long)rl * 1024 + (kt) * 64 + stg_col, \
                 &lds[(c) * 32768 + rl * 64 + lin_col]); \
    } \
} while (0)

#define STAGE_B(h, kt, c) do { \
    _Pragma("unroll") \
    for (int o = 0; o < 2; ++o) { \
        int rl = o * 128 + (h) * 32 + (stg_row & 31) + ((stg_row & 32) << 1); \
        gl2lds16(Bb + (long long)rl * 1024 + (kt) * 64 + stg_col, \
                 &lds[(c) * 32768 + 16384 + rl * 64 + lin_col]); \
    } \
} while (0)

#define LOAD_A(hm, c) do { \
    _Pragma("unroll") \
    for (int mt = 0; mt < 4; ++mt) { \
        const __bf16* p = &lds[(c) * 32768 + (wr * 128 + (hm) * 64 + mt * 16 + fm) * 64]; \
        af[mt][0] = *(const bf16x8*)&p[(fg * 8) ^ rsw]; \
        af[mt][1] = *(const bf16x8*)&p[(32 + fg * 8) ^ rsw]; \
    } \
} while (0)

#define LOAD_B(hn, c) do { \
    _Pragma("unroll") \
    for (int nt = 0; nt < 2; ++nt) { \
        const __bf16* p = &lds[(c) * 32768 + 16384 + (wc * 64 + (hn) * 32 + nt * 16 + fm) * 64]; \
        bv[(hn) * 2 + nt][0] = *(const bf16x8*)&p[(fg * 8) ^ rsw]; \
        bv[(hn) * 2 + nt][1] = *(const bf16x8*)&p[(32 + fg * 8) ^ rsw]; \
    } \
} while (0)

#define MFMA_Q(hm, hn) do { \
    __builtin_amdgcn_s_setprio(1); \
    _Pragma("unroll") \
    for (int mt = 0; mt < 4; ++mt) \
        _Pragma("unroll") \
        for (int nt = 0; nt < 2; ++nt) { \
            acc[(hm) * 4 + mt][(hn) * 2 + nt] = __builtin_amdgcn_mfma_f32_16x16x32_bf16( \
                af[mt][0], bv[(hn) * 2 + nt][0], acc[(hm) * 4 + mt][(hn) * 2 + nt], 0, 0, 0); \
            acc[(hm) * 4 + mt][(hn) * 2 + nt] = __builtin_amdgcn_mfma_f32_16x16x32_bf16( \
                af[mt][1], bv[(hn) * 2 + nt][1], acc[(hm) * 4 + mt][(hn) * 2 + nt], 0, 0, 0); \
        } \
    __builtin_amdgcn_s_setprio(0); \
} while (0)

__global__ __launch_bounds__(512, 2) void obig8(
    const __bf16* __restrict__ Xall, const __bf16* __restrict__ Mb, float* __restrict__ out)
{
    __shared__ __bf16 lds[65536];   // [buf0: A 32KB | B 32KB][buf1: A 32KB | B 32KB]

    const int id = blockIdx.x;                  // 0..511
    const int wg = (id & 7) * 64 + (id >> 3);   // bijective XCD swizzle: one z per XCD
    const int z = wg >> 6;                      // 0..7
    const int tile = wg & 63;
    const int tm = tile & 15, tn = tile >> 4;   // 16 m-tiles x 4 n-tiles
    const int path = z >> 2, b = z & 3;

    const __bf16* Xa = Xall + (path == 0 ? 16777216LL : 0LL)
                     + (long long)b * 4194304 + (long long)tm * 262144;
    const __bf16* Bb = Mb + (long long)path * 4194304 + (long long)b * 1048576
                     + (long long)tn * 262144;
    float* Ob = out + (long long)path * 16777216 + (long long)b * 4194304;

    const int t = threadIdx.x;
    const int lane = t & 63, wave = t >> 6;     // 8 waves: 2M x 4N
    const int wr = wave >> 2, wc = wave & 3;
    const int fm = lane & 15, fg = lane >> 4;
    const int stg_row = t >> 3;                 // 0..63
    const int lin_col = (t & 7) * 8;            // linear LDS dest col (elems)
    const int stg_col = ((t & 7) ^ (stg_row & 7)) * 8;  // inverse-swizzled global col
    const int rsw = (fm & 7) * 8;               // read-side swizzle XOR (elems)

    f32x4 acc[8][4];
#pragma unroll
    for (int u = 0; u < 8; ++u)
#pragma unroll
        for (int v = 0; v < 4; ++v) acc[u][v] = (f32x4){0.f, 0.f, 0.f, 0.f};

    bf16x8 af[4][2];   // current M-half: 4 mt x 2 ksub
    bf16x8 bv[8][2];   // whole tile's B: 4 nt x 2 ksub (both halves kept)

    // prologue: stage tiles 0 (buf0) and 1 (buf1) fully, consumption order
    STAGE_A(0, 0, 0); STAGE_B(0, 0, 0); STAGE_B(1, 0, 0); STAGE_A(1, 0, 0);
    STAGE_A(0, 1, 1); STAGE_B(0, 1, 1); STAGE_B(1, 1, 1); STAGE_A(1, 1, 1);
    VMCNT8;   // tile 0's 8 loads drained; tile 1's 8 in flight
    BARR;

    for (int kt = 0; kt < 14; ++kt) {
        const int c = kt & 1;
        // ---- phase 1: quadrant (Mh0, Nh0) ----
        LOAD_A(0, c);
        LOAD_B(0, c);
        BARR;
        MFMA_Q(0, 0);
        BARR;
        // ---- phase 2: quadrant (Mh0, Nh1); stage (t+2) Ah0 over consumed Ah0 ----
        LOAD_B(1, c);
        STAGE_A(0, kt + 2, c);
        BARR;
        MFMA_Q(0, 1);
        BARR;
        // ---- phase 3: quadrant (Mh1, Nh1); stage (t+2) Bh0 over consumed Bh0 ----
        LOAD_A(1, c);
        STAGE_B(0, kt + 2, c);
        BARR;
        MFMA_Q(1, 1);
        BARR;
        // ---- phase 4: quadrant (Mh1, Nh0); stage (t+2) Bh1+Ah1; ONE counted wait ----
        STAGE_B(1, kt + 2, c);
        STAGE_A(1, kt + 2, c);
        VMCNT8;                 // drains tile t+1's 8; leaves tile t+2's 8 in flight
        BARR;
        MFMA_Q(1, 0);
        BARR;
    }

    // ---- kt = 14 (buf 0): no staging; drain tile 15's loads at phase 4 ----
    {
        LOAD_A(0, 0);
        LOAD_B(0, 0);
        BARR;
        MFMA_Q(0, 0);
        BARR;
        LOAD_B(1, 0);
        BARR;
        MFMA_Q(0, 1);
        BARR;
        LOAD_A(1, 0);
        BARR;
        MFMA_Q(1, 1);
        BARR;
        VMCNT0;                 // tile 15's buffer fully valid
        BARR;
        MFMA_Q(1, 0);
        BARR;
    }

    // ---- kt = 15 (buf 1): fully resident, no barriers needed ----
    {
        LOAD_A(0, 1);
        LOAD_B(0, 1);
        MFMA_Q(0, 0);
        LOAD_B(1, 1);
        MFMA_Q(0, 1);
        LOAD_A(1, 1);
        MFMA_Q(1, 1);
        MFMA_Q(1, 0);
    }

    // ---- C write ----
    const int rq = fg * 4;
    float* op = Ob + (long long)(tm * 256 + wr * 128 + rq) * 1024 + tn * 256 + wc * 64 + fm;
#pragma unroll
    for (int mi = 0; mi < 8; ++mi)
#pragma unroll
        for (int ni = 0; ni < 4; ++ni)
#pragma unroll
            for (int r = 0; r < 4; ++r)
                op[(long long)(mi * 16 + r) * 1024 + ni * 16] = acc[mi][ni][r];
}

// ---------------- stats (partial) + softmax ----------------
// stats1: 8 chunk-blocks per plane-group -> partial (sum, sumsq) pairs.
__global__ __launch_bounds__(256) void stats1_kernel(const float* __restrict__ S,
                                                     float* __restrict__ pstat) {
    const int ch = blockIdx.x, pg = blockIdx.y;
    const float* s = S + (long long)pg * 65536 + ch * 8192;
    const int t = threadIdx.x;
    float sum = 0.f, sq = 0.f;
#pragma unroll
    for (int i = 0; i < 8; ++i) {
        float4 v = *(const float4*)&s[(i * 256 + t) * 4];
        sum += v.x + v.y + v.z + v.w;
        sq += v.x * v.x + v.y * v.y + v.z * v.z + v.w * v.w;
    }
#pragma unroll
    for (int off = 32; off; off >>= 1) {
        sum += __shfl_down(sum, off);
        sq  += __shfl_down(sq,  off);
    }
    __shared__ float r1[4], r2[4];
    int w = t >> 6;
    if ((t & 63) == 0) { r1[w] = sum; r2[w] = sq; }
    __syncthreads();
    if (t == 0) {
        pstat[(pg * 8 + ch) * 2 + 0] = r1[0] + r1[1] + r1[2] + r1[3];
        pstat[(pg * 8 + ch) * 2 + 1] = r2[0] + r2[1] + r2[2] + r2[3];
    }
}

// softmax: 4 rows per block, one wave per row, no __syncthreads.
__global__ __launch_bounds__(256) void softmax_kernel(const float* __restrict__ S,
                                                      const float* __restrict__ pstat,
                                                      __bf16* __restrict__ p_bf) {
    const int pg = blockIdx.y;
    float ts = 0.f, tq = 0.f;
#pragma unroll
    for (int i = 0; i < 8; ++i) {
        ts += pstat[(pg * 8 + i) * 2 + 0];
        tq += pstat[(pg * 8 + i) * 2 + 1];
    }
    const float mean = ts * (1.0f / 65536.0f);
    const float rstd = rsqrtf(tq * (1.0f / 65536.0f) - mean * mean + 1e-5f);

    const int wave = threadIdx.x >> 6, lane = threadIdx.x & 63;
    const int c = blockIdx.x * 4 + wave;
    const float* row = S + (long long)pg * 65536 + c * 256;
    float4 v = *(const float4*)&row[lane * 4];
    float x0 = (v.x - mean) * rstd, x1 = (v.y - mean) * rstd;
    float x2 = (v.z - mean) * rstd, x3 = (v.w - mean) * rstd;
    float m = fmaxf(fmaxf(x0, x1), fmaxf(x2, x3));
#pragma unroll
    for (int off = 32; off; off >>= 1) m = fmaxf(m, __shfl_xor(m, off));
    float e0 = expf(x0 - m), e1 = expf(x1 - m), e2 = expf(x2 - m), e3 = expf(x3 - m);
    float ssum = e0 + e1 + e2 + e3;
#pragma unroll
    for (int off = 32; off; off >>= 1) ssum += __shfl_xor(ssum, off);
    float inv = 1.0f / ssum;
    bf16x4 o = {(__bf16)(e0 * inv), (__bf16)(e1 * inv), (__bf16)(e2 * inv), (__bf16)(e3 * inv)};
    *(bf16x4*)&p_bf[(long long)pg * 65536 + c * 256 + lane * 4] = o;
}

extern "C" void kernel_launch(void* const* d_in, const int* in_sizes, int n_in,
                              void* d_out, int out_size, void* d_ws, size_t ws_size,
                              hipStream_t stream) {
    const float* emb1     = (const float*)d_in[0];
    const float* emb_all  = (const float*)d_in[1];
    const float* embd1    = (const float*)d_in[2];
    const float* emb_alld = (const float*)d_in[3];
    const float* Wq    = (const float*)d_in[4];
    const float* Wqd   = (const float*)d_in[5];
    const float* Wk0   = (const float*)d_in[6];
    const float* Wv0   = (const float*)d_in[7];
    const float* Wkd0  = (const float*)d_in[8];
    const float* Wvd0  = (const float*)d_in[9];
    const float* Wout  = (const float*)d_in[10];
    const float* Woutd = (const float*)d_in[11];
    float* out = (float*)d_out;

    float* ws = (float*)d_ws;
    // Gpart: 16,777,216 fl = 67 MB at ws[0..) -- OVERLAPS X_bf region in space,
    // disjoint in TIME: prep_x runs AFTER reduce_g (X_bf's only reader is obig8).
    float*  Gpart   = ws;
    __bf16* Mb_bf   = (__bf16*)ws;                    // 8,388,608 bf16 (aliases Gpart, late)
    __bf16* X_bf    = (__bf16*)(ws + 8388608);        // 33,554,432 bf16 [emb_all | emb_alld]
    __bf16* GT_bf   = (__bf16*)(ws + 25165824);       // 2,097,152 bf16
    __bf16* T_bf    = (__bf16*)(ws + 26214400);       // 2,097,152 bf16
    float*  S       = ws + 27262976;                  // 2,097,152 fp32
    __bf16* p_bf    = (__bf16*)(ws + 29360128);       // 2,097,152 bf16
    __bf16* PT_bf   = (__bf16*)(ws + 30408704);       // 2,097,152 bf16
    __bf16* Wq_bf   = (__bf16*)(ws + 31457280);       // 524,288 bf16
    __bf16* Wk_bf   = (__bf16*)(ws + 31719424);       // 131,072 bf16
    __bf16* WvT_bf  = (__bf16*)(ws + 31784960);       // 131,072 bf16
    __bf16* WoutR_bf= (__bf16*)(ws + 31850496);       // 2,097,152 bf16
    float*  st      = ws + 32899072;                  // 512 fl partials

    dim3 blk(256);

    // prep_w (weights region only, independent)
    prep_w<<<11264, blk, 0, stream>>>(Wq, Wqd, Wk0, Wv0, Wkd0, Wvd0, Wout, Woutd,
                                      Wq_bf, Wk_bf, WvT_bf, WoutR_bf);

    // GT = Xm^T @ Xn (256x256 tile, split-K x8) + reduce->bf16
    gram_mfma<<<dim3(8, 32), dim3(512), 0, stream>>>(emb1, emb_all, embd1, emb_alld, Gpart);
    reduce_g<<<2048, blk, 0, stream>>>(Gpart, GT_bf);

    // prep_x AFTER reduce_g: Gpart (67 MB) is dead now; X_bf may overwrite it.
    prep_x<<<dim3(16384, 2), blk, 0, stream>>>(emb_all, emb_alld, X_bf);

    // T = Wq_h @ G   (A=Wq_bf, B=GT)
    mfma_nt<__bf16><<<dim3(16, 32), blk, 0, stream>>>(
        Wq_bf, GT_bf, T_bf, 4, 256,
        262144, 0, 65536,  1048576, 262144, 65536,  1048576, 262144, 65536, 256, 1.0f);
    // S = scale * T @ Wk'^T
    mfma_nt<float><<<dim3(16, 32), blk, 0, stream>>>(
        T_bf, Wk_bf, S, 4, 256,
        1048576, 262144, 65536,  65536, 0, 0,  1048576, 262144, 65536, 256, 0.03125f);

    stats1_kernel<<<dim3(8, 32), blk, 0, stream>>>(S, st);
    softmax_kernel<<<dim3(64, 32), blk, 0, stream>>>(S, st, p_bf);

    // PT = WvT @ p^T
    mfma_nt<__bf16><<<dim3(16, 32), blk, 0, stream>>>(
        WvT_bf, p_bf, PT_bf, 4, 256,
        65536, 0, 0,  1048576, 262144, 65536,  1048576, 262144, 65536, 256, 1.0f);
    // Mb = WoutR @ PT^T   (M=1024)
    mfma_nt<__bf16><<<dim3(64, 32), blk, 0, stream>>>(
        WoutR_bf, PT_bf, Mb_bf, 16, 256,
        1048576, 0, 262144,  1048576, 262144, 65536,  4194304, 1048576, 256, 1024, 1.0f);

    // O = X @ Mb^T  (256x256 8-wave, deep-pipelined, T2 swizzle, one vmcnt/tile)
    obig8<<<dim3(512), dim3(512), 0, stream>>>(X_bf, Mb_bf, out);
}